// Round 10
// baseline (556.922 us; speedup 1.0000x reference)
//
#include <hip/hip_runtime.h>
#include <hip/hip_bf16.h>

#define B_   32
#define CIN  96
#define COUT 96
#define NP   3136
#define NE   8
#define HIDD 576

typedef short bf16x8 __attribute__((ext_vector_type(8)));
typedef float f32x4 __attribute__((ext_vector_type(4)));

__device__ __forceinline__ unsigned short f2bf(float f) {
  __hip_bfloat16 h = __float2bfloat16(f);
  unsigned short u; __builtin_memcpy(&u, &h, 2); return u;
}
__device__ __forceinline__ float bf2f(unsigned short u) {
  unsigned int v = ((unsigned int)u) << 16;
  float f; __builtin_memcpy(&f, &v, 4); return f;
}
__device__ __forceinline__ float u2f(unsigned int v) {
  float f; __builtin_memcpy(&f, &v, 4); return f;
}

// ---------------- kernel 1: transpose x -> x_t[b][p][c] bf16, + partial sums -
__global__ __launch_bounds__(256) void k_transpose(const float* __restrict__ x,
                                                   unsigned short* __restrict__ xt,
                                                   float* __restrict__ xpart) {
  __shared__ float tile[CIN][65];
  int bi = blockIdx.x; int b = bi / 49, pt = bi % 49; int p0 = pt * 64;
  int t = threadIdx.x;
  for (int j = t; j < CIN * 64; j += 256) {
    int c = j >> 6, pi = j & 63;
    tile[c][pi] = x[((size_t)(b * CIN + c)) * NP + p0 + pi];
  }
  __syncthreads();
  if (t < CIN) {
    float s = 0.f;
    for (int i = 0; i < 64; ++i) s += tile[t][i];
    xpart[((size_t)(b * 49 + pt)) * CIN + t] = s;
  }
  for (int j = t; j < 64 * CIN; j += 256) {
    int p = j / CIN, c = j % CIN;
    xt[((size_t)(b * NP + p0 + p)) * CIN + c] = f2bf(tile[c][p]);
  }
}

// ---------------- kernel 2: fused routers r1/rblk + BN scale/bias prep -------
__global__ __launch_bounds__(64) void k_front(const float* __restrict__ xpart,
    const float* __restrict__ wr1, const float* __restrict__ br1,
    const float* __restrict__ wr3, const float* __restrict__ br3,
    float* __restrict__ r1, float* __restrict__ rblk,
    const float* g1, const float* bt1, const float* m1, const float* v1,
    const float* g2, const float* bt2, const float* m2, const float* v2,
    const float* g3, const float* bt3, const float* m3, const float* v3,
    float* sc1, float* bi1, float* sc2, float* bi2, float* sc3, float* bi3) {
  int bi = blockIdx.x; int lane = threadIdx.x;
  if (bi < 512) {
    const float* wr; const float* br; float* dst; int id;
    if (bi < 256) { wr = wr1; br = br1; dst = r1;   id = bi; }
    else          { wr = wr3; br = br3; dst = rblk; id = bi - 256; }
    int b = id >> 3, e = id & 7;
    float s = 0.f;
    for (int c = lane; c < CIN; c += 64) {
      const float* xp = xpart + (size_t)b * 49 * CIN + c;
      float xm = 0.f;
#pragma unroll 7
      for (int k = 0; k < 49; ++k) xm += xp[k * CIN];
      s += xm * (1.0f / NP) * wr[e * CIN + c];
    }
    s += __shfl_xor(s, 1);  s += __shfl_xor(s, 2);  s += __shfl_xor(s, 4);
    s += __shfl_xor(s, 8);  s += __shfl_xor(s, 16); s += __shfl_xor(s, 32);
    if (lane == 0) dst[id] = 1.0f / (1.0f + __expf(-(s + br[e])));
  } else {
    int i = (bi - 512) * 64 + lane;
    if (i < HIDD) {
      float s = g1[i] * rsqrtf(v1[i] + 1e-5f); sc1[i] = s; bi1[i] = bt1[i] - m1[i] * s;
    } else if (i < 2 * HIDD) {
      int c = i - HIDD;
      float s = g2[c] * rsqrtf(v2[c] + 1e-5f); sc2[c] = s; bi2[c] = bt2[c] - m2[c] * s;
    } else if (i < 2 * HIDD + COUT) {
      int c = i - 2 * HIDD;
      float s = g3[c] * rsqrtf(v3[c] + 1e-5f); sc3[c] = s; bi3[c] = bt3[c] - m3[c] * s;
    }
  }
}

// ---------------- kernel 3: mix expert weights -> bf16 -----------------------
__global__ __launch_bounds__(256) void k_mixw(
    const float* __restrict__ w1, const float* __restrict__ r1, unsigned short* __restrict__ w1c,
    const float* __restrict__ w3, const float* __restrict__ rblk, unsigned short* __restrict__ w3c) {
  __shared__ float rsh[256];
  int bi = blockIdx.x; int t = threadIdx.x;
  const float* w; const float* r; unsigned short* dst; int oc0;
  if (bi < 216) { w = w1; r = r1;   dst = w1c; oc0 = bi * 256; }
  else          { w = w3; r = rblk; dst = w3c; oc0 = (bi - 216) * 256; }
  rsh[t] = r[t];
  __syncthreads();
  int oc = oc0 + t;
  float wv[NE];
#pragma unroll
  for (int e = 0; e < NE; ++e) wv[e] = w[(size_t)e * 55296 + oc];
  for (int b = 0; b < B_; ++b) {
    float a = 0.f;
#pragma unroll
    for (int e = 0; e < NE; ++e) a += rsh[b * 8 + e] * wv[e];
    dst[(size_t)b * 55296 + oc] = f2bf(a);
  }
}

// ---------------- kernel 4: expand GEMM + BN + ReLU6, y in [b][p][h] ---------
__global__ __launch_bounds__(256) void k_expand2(const unsigned short* __restrict__ xt,
    const unsigned short* __restrict__ w1c, const float* __restrict__ sc1,
    const float* __restrict__ bi1, unsigned short* __restrict__ y2,
    float* __restrict__ yspart) {
  __shared__ unsigned short As[64 * 104];   // w1c tile; reused as transpose buf T[64][72]
  __shared__ unsigned short Bs[64 * 104];   // xt tile
  int t = threadIdx.x;
  int pt = blockIdx.x;
  int p0 = pt * 64, o0 = blockIdx.y * 64, b = blockIdx.z;
  const unsigned short* ag = w1c + (size_t)b * 55296 + (size_t)o0 * 96;
  const unsigned short* bg = xt + ((size_t)b * NP + p0) * 96;
  for (int j = t; j < 768; j += 256) {
    int r = j / 12, ch = j % 12;
    *(int4*)(As + r * 104 + ch * 8) = *(const int4*)(ag + r * 96 + ch * 8);
    *(int4*)(Bs + r * 104 + ch * 8) = *(const int4*)(bg + r * 96 + ch * 8);
  }
  __syncthreads();
  int lane = t & 63, wv = t >> 6;
  int m = lane & 15, q = lane >> 4;
  f32x4 acc[4];
#pragma unroll
  for (int nt = 0; nt < 4; ++nt) acc[nt] = 0.f;
#pragma unroll
  for (int kk = 0; kk < 3; ++kk) {
    bf16x8 af = *(const bf16x8*)(As + (wv * 16 + m) * 104 + kk * 32 + q * 8);
#pragma unroll
    for (int nt = 0; nt < 4; ++nt) {
      bf16x8 bfb = *(const bf16x8*)(Bs + (nt * 16 + m) * 104 + kk * 32 + q * 8);
      acc[nt] = __builtin_amdgcn_mfma_f32_16x16x32_bf16(af, bfb, acc[nt], 0, 0, 0);
    }
  }
  __syncthreads();   // all LDS reads done; As is now free for reuse
  float sc[4], bb[4];
#pragma unroll
  for (int i = 0; i < 4; ++i) {
    int o = o0 + wv * 16 + q * 4 + i;
    sc[i] = sc1[o]; bb[i] = bi1[o];
  }
  float rs[4] = {0.f, 0.f, 0.f, 0.f};
  unsigned short* T = As;   // T stride 72 u16
#pragma unroll
  for (int nt = 0; nt < 4; ++nt) {
    unsigned short pk[4];
#pragma unroll
    for (int i = 0; i < 4; ++i) {
      float v = acc[nt][i] * sc[i] + bb[i];
      v = fminf(fmaxf(v, 0.f), 6.f);
      rs[i] += v;
      pk[i] = f2bf(v);
    }
    uint2 pv; __builtin_memcpy(&pv, pk, 8);
    *(uint2*)(T + (nt * 16 + m) * 72 + wv * 16 + q * 4) = pv;
  }
#pragma unroll
  for (int i = 0; i < 4; ++i) {
    float r = rs[i];
    r += __shfl_xor(r, 1); r += __shfl_xor(r, 2);
    r += __shfl_xor(r, 4); r += __shfl_xor(r, 8);
    if (m == 0)
      yspart[((size_t)b * 49 + pt) * HIDD + o0 + wv * 16 + q * 4 + i] = r;
  }
  __syncthreads();
  for (int j = t; j < 512; j += 256) {
    int r = j >> 3, ch = j & 7;
    *(int4*)(y2 + ((size_t)(b * NP + p0 + r)) * 576 + o0 + ch * 8) =
        *(const int4*)(T + r * 72 + ch * 8);
  }
}

// ---------------- kernel 5: fused router2 + tap premix (one block per batch) -
__global__ __launch_bounds__(256) void k_mid(const float* __restrict__ yspart,
    const float* __restrict__ wr2, const float* __restrict__ br2,
    const float* __restrict__ w2, const float* __restrict__ sc2,
    const float* __restrict__ bi2, float* __restrict__ kwt) {
  __shared__ float ysum_l[HIDD];
  __shared__ float r2_l[NE];
  int b = blockIdx.x, t = threadIdx.x;
  const float* yp = yspart + (size_t)b * 49 * HIDD;
  for (int c = t; c < HIDD; c += 256) {
    float s = 0.f;
#pragma unroll 7
    for (int k = 0; k < 49; ++k) s += yp[k * HIDD + c];
    ysum_l[c] = s;
  }
  __syncthreads();
  int wv = t >> 6, lane = t & 63;
  for (int e = wv; e < NE; e += 4) {
    float s = 0.f;
    for (int h = lane; h < HIDD; h += 64)
      s += ysum_l[h] * (1.0f / NP) * wr2[e * HIDD + h];
    s += __shfl_xor(s, 1);  s += __shfl_xor(s, 2);  s += __shfl_xor(s, 4);
    s += __shfl_xor(s, 8);  s += __shfl_xor(s, 16); s += __shfl_xor(s, 32);
    if (lane == 0) r2_l[e] = 1.0f / (1.0f + __expf(-(s + br2[e])));
  }
  __syncthreads();
  float rr[NE];
#pragma unroll
  for (int e = 0; e < NE; ++e) rr[e] = r2_l[e];
  for (int c = t; c < HIDD; c += 256) {
    float sc = sc2[c];
    float* dst = kwt + (size_t)b * 5760 + c;
#pragma unroll
    for (int k = 0; k < 9; ++k) {
      float s = 0.f;
#pragma unroll
      for (int e = 0; e < NE; ++e) s += rr[e] * w2[((size_t)e * HIDD + c) * 9 + k];
      dst[k * 576] = s * sc;
    }
    dst[9 * 576] = bi2[c];
  }
}

// ---------------- kernel 6: FUSED dwise+project, CHUNK-PIPELINED -------------
// Identical to round 9 EXCEPT the dwise rotation: explicit named-register
// rotation (proven SCAT3 pattern) instead of float* + switch. Round 9's
// address-taking (&o0) defeated mem2reg -> o0/o1/o2 + taps spilled to scratch
// (VGPR_Count 40, FETCH 531 MB, WRITE 178 MB = scratch RMW traffic). Rule #20.
__global__ __launch_bounds__(512, 6) void k_dwproj2(const unsigned short* __restrict__ y2,
    const float* __restrict__ kwt, const unsigned short* __restrict__ w3c,
    const float* __restrict__ sc3, const float* __restrict__ bi3,
    const float* __restrict__ x, float* __restrict__ out) {
  __shared__ unsigned short zbuf[2 * 56 * 72];  // 16128 B, chunk z dbuf
  __shared__ unsigned short As[2 * 96 * 72];    // 27648 B, w3c chunk dbuf
  int t = threadIdx.x;
  int hr = blockIdx.x, b = blockIdx.z;
  int h = (hr & 7) * 7 + (hr >> 3);             // XCD-contiguous row band
  const unsigned short* ag = w3c + (size_t)b * 55296;

  // ---- A staging lane map (round-7 proven): rows 0..63 all, 64..95 t<256 ---
  int r0 = t >> 3, c8 = t & 7;
  int r1 = 64 + (t >> 3);
  bool two = (t < 256);
  int4 ra0, ra1;
#define LOADA(kc) do {                                                        \
    ra0 = *(const int4*)(ag + (size_t)r0 * 576 + (kc) * 64 + c8 * 8);         \
    if (two) ra1 = *(const int4*)(ag + (size_t)r1 * 576 + (kc) * 64 + c8 * 8); \
  } while (0)
#define WRITEA(kc) do {                                                       \
    unsigned short* ad = As + ((kc) & 1) * (96 * 72);                         \
    *(int4*)(ad + r0 * 72 + c8 * 8) = ra0;                                    \
    if (two) *(int4*)(ad + r1 * 72 + c8 * 8) = ra1;                           \
  } while (0)

  // ---- dwise task map: chl = channel-in-chunk, seg = 7-px segment ----------
  int chl = t & 63, seg = t >> 6;
  bool okU = (h > 0), okD = (h < 55);
  int rU = okU ? (h - 1) : h;
  int rD = okD ? (h + 1) : h;

  // Explicit named-register rotation (no address-taking — rule #20):
  // col j contributes tk2-family to output j-1 (A, stored), tk1 to output j
  // (Bv), tk0 to output j+1 (Cv). A reset EVERY column.
#define DWCHUNK(ck) do {                                                      \
    int ch = (ck) * 64 + chl;                                                 \
    const float* kp = kwt + (size_t)b * 5760 + ch;                            \
    float tk0 = kp[0], tk1 = kp[576], tk2 = kp[1152];                         \
    float tk3 = kp[1728], tk4 = kp[2304], tk5 = kp[2880];                     \
    float tk6 = kp[3456], tk7 = kp[4032], tk8 = kp[4608];                     \
    float tbv = kp[5184];                                                     \
    const unsigned short* yU = y2 + ((size_t)(b * NP + rU * 56)) * 576 + ch;  \
    const unsigned short* yC = y2 + ((size_t)(b * NP + h  * 56)) * 576 + ch;  \
    const unsigned short* yD = y2 + ((size_t)(b * NP + rD * 56)) * 576 + ch;  \
    unsigned short* zb = zbuf + ((ck) & 1) * (56 * 72) + chl;                 \
    float o0 = tbv, o1 = tbv, o2 = tbv;                                       \
    int j0 = seg * 7 - 1;                                                     \
    SCATs(o0, o1, o2, j0,     false);                                         \
    SCATs(o1, o2, o0, j0 + 1, false);                                         \
    SCATs(o2, o0, o1, j0 + 2, true);                                          \
    SCATs(o0, o1, o2, j0 + 3, true);                                          \
    SCATs(o1, o2, o0, j0 + 4, true);                                          \
    SCATs(o2, o0, o1, j0 + 5, true);                                          \
    SCATs(o0, o1, o2, j0 + 6, true);                                          \
    SCATs(o1, o2, o0, j0 + 7, true);                                          \
    SCATs(o2, o0, o1, j0 + 8, true);                                          \
  } while (0)

#define SCATs(A, Bv, Cv, j, STORE) do {                                       \
    float dU = 0.f, dC = 0.f, dD = 0.f;                                       \
    if ((unsigned)(j) < 56u) {                                                \
      if (okU) dU = bf2f(yU[(size_t)(j) * 576]);                              \
      dC = bf2f(yC[(size_t)(j) * 576]);                                       \
      if (okD) dD = bf2f(yD[(size_t)(j) * 576]);                              \
    }                                                                         \
    A  += dU * tk2 + dC * tk5 + dD * tk8;                                     \
    Bv += dU * tk1 + dC * tk4 + dD * tk7;                                     \
    Cv += dU * tk0 + dC * tk3 + dD * tk6;                                     \
    if (STORE)                                                                \
      zb[(size_t)((j) - 1) * 72] = f2bf(fminf(fmaxf(A, 0.f), 6.f));           \
    A = tbv;                                                                  \
  } while (0)

  // ---- GEMM lane map (round-7 proven): 8 waves = 2 o-halves x 4 px-16ths ---
  int lane = t & 63, wv = t >> 6;
  int wr = wv >> 2, wc = wv & 3;
  int m = lane & 15, q = lane >> 4;
  int px = wc * 16 + m;
  int pxr = (px < 56) ? px : 55;
  f32x4 acc0, acc1, acc2;
  acc0 = 0.f; acc1 = 0.f; acc2 = 0.f;

#define COMPUTE(kc) do {                                                      \
    const unsigned short* ab = As + ((kc) & 1) * (96 * 72);                   \
    const unsigned short* zr = zbuf + ((kc) & 1) * (56 * 72);                 \
    _Pragma("unroll") for (int kk = 0; kk < 2; ++kk) {                        \
      bf16x8 bfv = *(const bf16x8*)(zr + pxr * 72 + kk * 32 + q * 8);         \
      bf16x8 af0 = *(const bf16x8*)(ab + (wr * 48 +  0 + m) * 72 + kk * 32 + q * 8); \
      bf16x8 af1 = *(const bf16x8*)(ab + (wr * 48 + 16 + m) * 72 + kk * 32 + q * 8); \
      bf16x8 af2 = *(const bf16x8*)(ab + (wr * 48 + 32 + m) * 72 + kk * 32 + q * 8); \
      acc0 = __builtin_amdgcn_mfma_f32_16x16x32_bf16(af0, bfv, acc0, 0, 0, 0); \
      acc1 = __builtin_amdgcn_mfma_f32_16x16x32_bf16(af1, bfv, acc1, 0, 0, 0); \
      acc2 = __builtin_amdgcn_mfma_f32_16x16x32_bf16(af2, bfv, acc2, 0, 0, 0); \
    } } while (0)

  // ---- prologue: chunk 0 ---------------------------------------------------
  LOADA(0);
  DWCHUNK(0);
  WRITEA(0);
  __syncthreads();

  // ---- pipelined main loop: one barrier per chunk --------------------------
#pragma unroll 1
  for (int kc = 0; kc < 8; ++kc) {
    LOADA(kc + 1);        // w3c chunk kc+1 -> regs (lands during dwise+MFMA)
    DWCHUNK(kc + 1);      // dwise chunk kc+1 -> zbuf[(kc+1)&1]  (VALU + y2 loads)
    COMPUTE(kc);          // MFMA chunk kc from As[kc&1], zbuf[kc&1]
    WRITEA(kc + 1);       // regs -> As[(kc+1)&1] (implicit vmcnt wait)
    __syncthreads();
  }
  COMPUTE(8);

#undef COMPUTE
#undef SCATs
#undef DWCHUNK
#undef LOADA
#undef WRITEA

  // ---- epilogue: BN + residual ---------------------------------------------
  if (px < 56) {
    size_t pbase = (size_t)b * COUT * NP + (size_t)h * 56 + px;
#define EPI(ACC, a) do {                                                      \
    _Pragma("unroll") for (int i = 0; i < 4; ++i) {                           \
      int o = wr * 48 + (a) * 16 + q * 4 + i;                                 \
      size_t idx = pbase + (size_t)o * NP;                                    \
      out[idx] = ACC[i] * sc3[o] + bi3[o] + x[idx];                           \
    } } while (0)
    EPI(acc0, 0); EPI(acc1, 1); EPI(acc2, 2);
#undef EPI
  }
}

// ---------------- workspace layout (bytes) -----------------------------------
#define OFF_XT     ((size_t)0)           // 19267584 (dead after expand)
#define OFF_KWT    OFF_XT                // 737280, aliases xt
#define OFF_Y      ((size_t)19267584)    // 115605504  y2 [b][p][h] bf16
#define OFF_Z      ((size_t)134873088)   // (dead; kept for xpart/yspart aliasing)
#define OFF_XPART  OFF_Z                 // 602112
#define OFF_YSPART (OFF_Z + 602112)      // 3612672
#define OFF_W1C    ((size_t)250478592)   // 3538944
#define OFF_W3C    ((size_t)254017536)   // 3538944
#define OFF_R1     ((size_t)257642496)   // 1024
#define OFF_RBLK   ((size_t)257643520)   // 1024
#define OFF_SC1    ((size_t)257645568)   // 2304
#define OFF_BI1    ((size_t)257647872)   // 2304
#define OFF_SC2    ((size_t)257650176)   // 2304
#define OFF_BI2    ((size_t)257652480)   // 2304
#define OFF_SC3    ((size_t)257654784)   // 384
#define OFF_BI3    ((size_t)257655168)   // 384

extern "C" void kernel_launch(void* const* d_in, const int* in_sizes, int n_in,
                              void* d_out, int out_size, void* d_ws, size_t ws_size,
                              hipStream_t stream) {
  const float* x   = (const float*)d_in[0];
  const float* wr1 = (const float*)d_in[1];
  const float* br1 = (const float*)d_in[2];
  const float* w1  = (const float*)d_in[3];
  const float* g1  = (const float*)d_in[4];
  const float* bt1 = (const float*)d_in[5];
  const float* m1  = (const float*)d_in[6];
  const float* v1  = (const float*)d_in[7];
  const float* wr2 = (const float*)d_in[8];
  const float* br2 = (const float*)d_in[9];
  const float* w2  = (const float*)d_in[10];
  const float* g2  = (const float*)d_in[11];
  const float* bt2 = (const float*)d_in[12];
  const float* m2  = (const float*)d_in[13];
  const float* v2  = (const float*)d_in[14];
  const float* w3  = (const float*)d_in[15];
  const float* g3  = (const float*)d_in[16];
  const float* bt3 = (const float*)d_in[17];
  const float* m3  = (const float*)d_in[18];
  const float* v3  = (const float*)d_in[19];
  const float* wr3 = (const float*)d_in[20];
  const float* br3 = (const float*)d_in[21];
  float* out = (float*)d_out;
  char* ws = (char*)d_ws;

  unsigned short* xt     = (unsigned short*)(ws + OFF_XT);
  unsigned short* y2     = (unsigned short*)(ws + OFF_Y);
  unsigned short* w1c    = (unsigned short*)(ws + OFF_W1C);
  unsigned short* w3c    = (unsigned short*)(ws + OFF_W3C);
  float* xpart  = (float*)(ws + OFF_XPART);
  float* yspart = (float*)(ws + OFF_YSPART);
  float* r1     = (float*)(ws + OFF_R1);
  float* rblk   = (float*)(ws + OFF_RBLK);
  float* sc1    = (float*)(ws + OFF_SC1);
  float* bi1    = (float*)(ws + OFF_BI1);
  float* sc2    = (float*)(ws + OFF_SC2);
  float* bi2    = (float*)(ws + OFF_BI2);
  float* sc3    = (float*)(ws + OFF_SC3);
  float* bi3    = (float*)(ws + OFF_BI3);
  float* kwt    = (float*)(ws + OFF_KWT);

  k_transpose<<<32 * 49, 256, 0, stream>>>(x, xt, xpart);
  k_front<<<532, 64, 0, stream>>>(xpart, wr1, br1, wr3, br3, r1, rblk,
                                  g1, bt1, m1, v1, g2, bt2, m2, v2, g3, bt3, m3, v3,
                                  sc1, bi1, sc2, bi2, sc3, bi3);
  k_mixw<<<432, 256, 0, stream>>>(w1, r1, w1c, w3, rblk, w3c);
  k_expand2<<<dim3(49, 9, 32), 256, 0, stream>>>(xt, w1c, sc1, bi1, y2, yspart);
  k_mid<<<32, 256, 0, stream>>>(yspart, wr2, br2, w2, sc2, bi2, kwt);
  k_dwproj2<<<dim3(56, 1, 32), 512, 0, stream>>>(y2, kwt, w3c, sc3, bi3, x, out);
}

// Round 11
// 422.835 us; speedup vs baseline: 1.3171x; 1.3171x over previous
//
#include <hip/hip_runtime.h>
#include <hip/hip_bf16.h>

#define B_   32
#define CIN  96
#define COUT 96
#define NP   3136
#define NE   8
#define HIDD 576

typedef short bf16x8 __attribute__((ext_vector_type(8)));
typedef float f32x4 __attribute__((ext_vector_type(4)));

__device__ __forceinline__ unsigned short f2bf(float f) {
  __hip_bfloat16 h = __float2bfloat16(f);
  unsigned short u; __builtin_memcpy(&u, &h, 2); return u;
}
__device__ __forceinline__ float bf2f(unsigned short u) {
  unsigned int v = ((unsigned int)u) << 16;
  float f; __builtin_memcpy(&f, &v, 4); return f;
}
__device__ __forceinline__ float u2f(unsigned int v) {
  float f; __builtin_memcpy(&f, &v, 4); return f;
}

// ---------------- kernel 1: transpose x -> x_t[b][p][c] bf16, + partial sums -
__global__ __launch_bounds__(256) void k_transpose(const float* __restrict__ x,
                                                   unsigned short* __restrict__ xt,
                                                   float* __restrict__ xpart) {
  __shared__ float tile[CIN][65];
  int bi = blockIdx.x; int b = bi / 49, pt = bi % 49; int p0 = pt * 64;
  int t = threadIdx.x;
  for (int j = t; j < CIN * 64; j += 256) {
    int c = j >> 6, pi = j & 63;
    tile[c][pi] = x[((size_t)(b * CIN + c)) * NP + p0 + pi];
  }
  __syncthreads();
  if (t < CIN) {
    float s = 0.f;
    for (int i = 0; i < 64; ++i) s += tile[t][i];
    xpart[((size_t)(b * 49 + pt)) * CIN + t] = s;
  }
  for (int j = t; j < 64 * CIN; j += 256) {
    int p = j / CIN, c = j % CIN;
    xt[((size_t)(b * NP + p0 + p)) * CIN + c] = f2bf(tile[c][p]);
  }
}

// ---------------- kernel 2: fused routers r1/rblk + BN scale/bias prep -------
__global__ __launch_bounds__(64) void k_front(const float* __restrict__ xpart,
    const float* __restrict__ wr1, const float* __restrict__ br1,
    const float* __restrict__ wr3, const float* __restrict__ br3,
    float* __restrict__ r1, float* __restrict__ rblk,
    const float* g1, const float* bt1, const float* m1, const float* v1,
    const float* g2, const float* bt2, const float* m2, const float* v2,
    const float* g3, const float* bt3, const float* m3, const float* v3,
    float* sc1, float* bi1, float* sc2, float* bi2, float* sc3, float* bi3) {
  int bi = blockIdx.x; int lane = threadIdx.x;
  if (bi < 512) {
    const float* wr; const float* br; float* dst; int id;
    if (bi < 256) { wr = wr1; br = br1; dst = r1;   id = bi; }
    else          { wr = wr3; br = br3; dst = rblk; id = bi - 256; }
    int b = id >> 3, e = id & 7;
    float s = 0.f;
    for (int c = lane; c < CIN; c += 64) {
      const float* xp = xpart + (size_t)b * 49 * CIN + c;
      float xm = 0.f;
#pragma unroll 7
      for (int k = 0; k < 49; ++k) xm += xp[k * CIN];
      s += xm * (1.0f / NP) * wr[e * CIN + c];
    }
    s += __shfl_xor(s, 1);  s += __shfl_xor(s, 2);  s += __shfl_xor(s, 4);
    s += __shfl_xor(s, 8);  s += __shfl_xor(s, 16); s += __shfl_xor(s, 32);
    if (lane == 0) dst[id] = 1.0f / (1.0f + __expf(-(s + br[e])));
  } else {
    int i = (bi - 512) * 64 + lane;
    if (i < HIDD) {
      float s = g1[i] * rsqrtf(v1[i] + 1e-5f); sc1[i] = s; bi1[i] = bt1[i] - m1[i] * s;
    } else if (i < 2 * HIDD) {
      int c = i - HIDD;
      float s = g2[c] * rsqrtf(v2[c] + 1e-5f); sc2[c] = s; bi2[c] = bt2[c] - m2[c] * s;
    } else if (i < 2 * HIDD + COUT) {
      int c = i - 2 * HIDD;
      float s = g3[c] * rsqrtf(v3[c] + 1e-5f); sc3[c] = s; bi3[c] = bt3[c] - m3[c] * s;
    }
  }
}

// ---------------- kernel 3: mix expert weights -> bf16 -----------------------
__global__ __launch_bounds__(256) void k_mixw(
    const float* __restrict__ w1, const float* __restrict__ r1, unsigned short* __restrict__ w1c,
    const float* __restrict__ w3, const float* __restrict__ rblk, unsigned short* __restrict__ w3c) {
  __shared__ float rsh[256];
  int bi = blockIdx.x; int t = threadIdx.x;
  const float* w; const float* r; unsigned short* dst; int oc0;
  if (bi < 216) { w = w1; r = r1;   dst = w1c; oc0 = bi * 256; }
  else          { w = w3; r = rblk; dst = w3c; oc0 = (bi - 216) * 256; }
  rsh[t] = r[t];
  __syncthreads();
  int oc = oc0 + t;
  float wv[NE];
#pragma unroll
  for (int e = 0; e < NE; ++e) wv[e] = w[(size_t)e * 55296 + oc];
  for (int b = 0; b < B_; ++b) {
    float a = 0.f;
#pragma unroll
    for (int e = 0; e < NE; ++e) a += rsh[b * 8 + e] * wv[e];
    dst[(size_t)b * 55296 + oc] = f2bf(a);
  }
}

// ---------------- kernel 4: expand GEMM + BN + ReLU6, y in [b][p][h] ---------
__global__ __launch_bounds__(256) void k_expand2(const unsigned short* __restrict__ xt,
    const unsigned short* __restrict__ w1c, const float* __restrict__ sc1,
    const float* __restrict__ bi1, unsigned short* __restrict__ y2,
    float* __restrict__ yspart) {
  __shared__ unsigned short As[64 * 104];   // w1c tile; reused as transpose buf T[64][72]
  __shared__ unsigned short Bs[64 * 104];   // xt tile
  int t = threadIdx.x;
  int pt = blockIdx.x;
  int p0 = pt * 64, o0 = blockIdx.y * 64, b = blockIdx.z;
  const unsigned short* ag = w1c + (size_t)b * 55296 + (size_t)o0 * 96;
  const unsigned short* bg = xt + ((size_t)b * NP + p0) * 96;
  for (int j = t; j < 768; j += 256) {
    int r = j / 12, ch = j % 12;
    *(int4*)(As + r * 104 + ch * 8) = *(const int4*)(ag + r * 96 + ch * 8);
    *(int4*)(Bs + r * 104 + ch * 8) = *(const int4*)(bg + r * 96 + ch * 8);
  }
  __syncthreads();
  int lane = t & 63, wv = t >> 6;
  int m = lane & 15, q = lane >> 4;
  f32x4 acc[4];
#pragma unroll
  for (int nt = 0; nt < 4; ++nt) acc[nt] = 0.f;
#pragma unroll
  for (int kk = 0; kk < 3; ++kk) {
    bf16x8 af = *(const bf16x8*)(As + (wv * 16 + m) * 104 + kk * 32 + q * 8);
#pragma unroll
    for (int nt = 0; nt < 4; ++nt) {
      bf16x8 bfb = *(const bf16x8*)(Bs + (nt * 16 + m) * 104 + kk * 32 + q * 8);
      acc[nt] = __builtin_amdgcn_mfma_f32_16x16x32_bf16(af, bfb, acc[nt], 0, 0, 0);
    }
  }
  __syncthreads();   // all LDS reads done; As is now free for reuse
  float sc[4], bb[4];
#pragma unroll
  for (int i = 0; i < 4; ++i) {
    int o = o0 + wv * 16 + q * 4 + i;
    sc[i] = sc1[o]; bb[i] = bi1[o];
  }
  float rs[4] = {0.f, 0.f, 0.f, 0.f};
  unsigned short* T = As;   // T stride 72 u16
#pragma unroll
  for (int nt = 0; nt < 4; ++nt) {
    unsigned short pk[4];
#pragma unroll
    for (int i = 0; i < 4; ++i) {
      float v = acc[nt][i] * sc[i] + bb[i];
      v = fminf(fmaxf(v, 0.f), 6.f);
      rs[i] += v;
      pk[i] = f2bf(v);
    }
    uint2 pv; __builtin_memcpy(&pv, pk, 8);
    *(uint2*)(T + (nt * 16 + m) * 72 + wv * 16 + q * 4) = pv;
  }
#pragma unroll
  for (int i = 0; i < 4; ++i) {
    float r = rs[i];
    r += __shfl_xor(r, 1); r += __shfl_xor(r, 2);
    r += __shfl_xor(r, 4); r += __shfl_xor(r, 8);
    if (m == 0)
      yspart[((size_t)b * 49 + pt) * HIDD + o0 + wv * 16 + q * 4 + i] = r;
  }
  __syncthreads();
  for (int j = t; j < 512; j += 256) {
    int r = j >> 3, ch = j & 7;
    *(int4*)(y2 + ((size_t)(b * NP + p0 + r)) * 576 + o0 + ch * 8) =
        *(const int4*)(T + r * 72 + ch * 8);
  }
}

// ---------------- kernel 5: fused router2 + tap premix (one block per batch) -
__global__ __launch_bounds__(256) void k_mid(const float* __restrict__ yspart,
    const float* __restrict__ wr2, const float* __restrict__ br2,
    const float* __restrict__ w2, const float* __restrict__ sc2,
    const float* __restrict__ bi2, float* __restrict__ kwt) {
  __shared__ float ysum_l[HIDD];
  __shared__ float r2_l[NE];
  int b = blockIdx.x, t = threadIdx.x;
  const float* yp = yspart + (size_t)b * 49 * HIDD;
  for (int c = t; c < HIDD; c += 256) {
    float s = 0.f;
#pragma unroll 7
    for (int k = 0; k < 49; ++k) s += yp[k * HIDD + c];
    ysum_l[c] = s;
  }
  __syncthreads();
  int wv = t >> 6, lane = t & 63;
  for (int e = wv; e < NE; e += 4) {
    float s = 0.f;
    for (int h = lane; h < HIDD; h += 64)
      s += ysum_l[h] * (1.0f / NP) * wr2[e * HIDD + h];
    s += __shfl_xor(s, 1);  s += __shfl_xor(s, 2);  s += __shfl_xor(s, 4);
    s += __shfl_xor(s, 8);  s += __shfl_xor(s, 16); s += __shfl_xor(s, 32);
    if (lane == 0) r2_l[e] = 1.0f / (1.0f + __expf(-(s + br2[e])));
  }
  __syncthreads();
  float rr[NE];
#pragma unroll
  for (int e = 0; e < NE; ++e) rr[e] = r2_l[e];
  for (int c = t; c < HIDD; c += 256) {
    float sc = sc2[c];
    float* dst = kwt + (size_t)b * 5760 + c;
#pragma unroll
    for (int k = 0; k < 9; ++k) {
      float s = 0.f;
#pragma unroll
      for (int e = 0; e < NE; ++e) s += rr[e] * w2[((size_t)e * HIDD + c) * 9 + k];
      dst[k * 576] = s * sc;
    }
    dst[9 * 576] = bi2[c];
  }
}

// ---------------- kernel 6: FUSED dwise+project, CHUNK-PIPELINED -------------
// Identical to round 10 EXCEPT __launch_bounds__(512, 4) (was (512, 6)).
// The min-waves/EU=6 arg capped the allocator at ~85 VGPRs < live state ->
// scratch spill (VGPR_Count 40, FETCH 530 MB, WRITE 184 MB of scratch RMW,
// 360 us). (512,4) = 128-VGPR cap, the regime where rounds 5/7 compiled
// spill-free at 52 VGPR. 2 blocks/CU (16 waves) via LDS 43.8 KB.
__global__ __launch_bounds__(512, 4) void k_dwproj2(const unsigned short* __restrict__ y2,
    const float* __restrict__ kwt, const unsigned short* __restrict__ w3c,
    const float* __restrict__ sc3, const float* __restrict__ bi3,
    const float* __restrict__ x, float* __restrict__ out) {
  __shared__ unsigned short zbuf[2 * 56 * 72];  // 16128 B, chunk z dbuf
  __shared__ unsigned short As[2 * 96 * 72];    // 27648 B, w3c chunk dbuf
  int t = threadIdx.x;
  int hr = blockIdx.x, b = blockIdx.z;
  int h = (hr & 7) * 7 + (hr >> 3);             // XCD-contiguous row band
  const unsigned short* ag = w3c + (size_t)b * 55296;

  // ---- A staging lane map (round-7 proven): rows 0..63 all, 64..95 t<256 ---
  int r0 = t >> 3, c8 = t & 7;
  int r1 = 64 + (t >> 3);
  bool two = (t < 256);
  int4 ra0, ra1;
#define LOADA(kc) do {                                                        \
    ra0 = *(const int4*)(ag + (size_t)r0 * 576 + (kc) * 64 + c8 * 8);         \
    if (two) ra1 = *(const int4*)(ag + (size_t)r1 * 576 + (kc) * 64 + c8 * 8); \
  } while (0)
#define WRITEA(kc) do {                                                       \
    unsigned short* ad = As + ((kc) & 1) * (96 * 72);                         \
    *(int4*)(ad + r0 * 72 + c8 * 8) = ra0;                                    \
    if (two) *(int4*)(ad + r1 * 72 + c8 * 8) = ra1;                           \
  } while (0)

  // ---- dwise task map: chl = channel-in-chunk, seg = 7-px segment ----------
  int chl = t & 63, seg = t >> 6;
  bool okU = (h > 0), okD = (h < 55);
  int rU = okU ? (h - 1) : h;
  int rD = okD ? (h + 1) : h;

  // Explicit named-register rotation: col j contributes tk2-family to output
  // j-1 (A, stored), tk1 to output j (Bv), tk0 to output j+1 (Cv). A reset
  // EVERY column.
#define DWCHUNK(ck) do {                                                      \
    int ch = (ck) * 64 + chl;                                                 \
    const float* kp = kwt + (size_t)b * 5760 + ch;                            \
    float tk0 = kp[0], tk1 = kp[576], tk2 = kp[1152];                         \
    float tk3 = kp[1728], tk4 = kp[2304], tk5 = kp[2880];                     \
    float tk6 = kp[3456], tk7 = kp[4032], tk8 = kp[4608];                     \
    float tbv = kp[5184];                                                     \
    const unsigned short* yU = y2 + ((size_t)(b * NP + rU * 56)) * 576 + ch;  \
    const unsigned short* yC = y2 + ((size_t)(b * NP + h  * 56)) * 576 + ch;  \
    const unsigned short* yD = y2 + ((size_t)(b * NP + rD * 56)) * 576 + ch;  \
    unsigned short* zb = zbuf + ((ck) & 1) * (56 * 72) + chl;                 \
    float o0 = tbv, o1 = tbv, o2 = tbv;                                       \
    int j0 = seg * 7 - 1;                                                     \
    SCATs(o0, o1, o2, j0,     false);                                         \
    SCATs(o1, o2, o0, j0 + 1, false);                                         \
    SCATs(o2, o0, o1, j0 + 2, true);                                          \
    SCATs(o0, o1, o2, j0 + 3, true);                                          \
    SCATs(o1, o2, o0, j0 + 4, true);                                          \
    SCATs(o2, o0, o1, j0 + 5, true);                                          \
    SCATs(o0, o1, o2, j0 + 6, true);                                          \
    SCATs(o1, o2, o0, j0 + 7, true);                                          \
    SCATs(o2, o0, o1, j0 + 8, true);                                          \
  } while (0)

#define SCATs(A, Bv, Cv, j, STORE) do {                                       \
    float dU = 0.f, dC = 0.f, dD = 0.f;                                       \
    if ((unsigned)(j) < 56u) {                                                \
      if (okU) dU = bf2f(yU[(size_t)(j) * 576]);                              \
      dC = bf2f(yC[(size_t)(j) * 576]);                                       \
      if (okD) dD = bf2f(yD[(size_t)(j) * 576]);                              \
    }                                                                         \
    A  += dU * tk2 + dC * tk5 + dD * tk8;                                     \
    Bv += dU * tk1 + dC * tk4 + dD * tk7;                                     \
    Cv += dU * tk0 + dC * tk3 + dD * tk6;                                     \
    if (STORE)                                                                \
      zb[(size_t)((j) - 1) * 72] = f2bf(fminf(fmaxf(A, 0.f), 6.f));           \
    A = tbv;                                                                  \
  } while (0)

  // ---- GEMM lane map (round-7 proven): 8 waves = 2 o-halves x 4 px-16ths ---
  int lane = t & 63, wv = t >> 6;
  int wr = wv >> 2, wc = wv & 3;
  int m = lane & 15, q = lane >> 4;
  int px = wc * 16 + m;
  int pxr = (px < 56) ? px : 55;
  f32x4 acc0, acc1, acc2;
  acc0 = 0.f; acc1 = 0.f; acc2 = 0.f;

#define COMPUTE(kc) do {                                                      \
    const unsigned short* ab = As + ((kc) & 1) * (96 * 72);                   \
    const unsigned short* zr = zbuf + ((kc) & 1) * (56 * 72);                 \
    _Pragma("unroll") for (int kk = 0; kk < 2; ++kk) {                        \
      bf16x8 bfv = *(const bf16x8*)(zr + pxr * 72 + kk * 32 + q * 8);         \
      bf16x8 af0 = *(const bf16x8*)(ab + (wr * 48 +  0 + m) * 72 + kk * 32 + q * 8); \
      bf16x8 af1 = *(const bf16x8*)(ab + (wr * 48 + 16 + m) * 72 + kk * 32 + q * 8); \
      bf16x8 af2 = *(const bf16x8*)(ab + (wr * 48 + 32 + m) * 72 + kk * 32 + q * 8); \
      acc0 = __builtin_amdgcn_mfma_f32_16x16x32_bf16(af0, bfv, acc0, 0, 0, 0); \
      acc1 = __builtin_amdgcn_mfma_f32_16x16x32_bf16(af1, bfv, acc1, 0, 0, 0); \
      acc2 = __builtin_amdgcn_mfma_f32_16x16x32_bf16(af2, bfv, acc2, 0, 0, 0); \
    } } while (0)

  // ---- prologue: chunk 0 ---------------------------------------------------
  LOADA(0);
  DWCHUNK(0);
  WRITEA(0);
  __syncthreads();

  // ---- pipelined main loop: one barrier per chunk --------------------------
#pragma unroll 1
  for (int kc = 0; kc < 8; ++kc) {
    LOADA(kc + 1);        // w3c chunk kc+1 -> regs (lands during dwise+MFMA)
    DWCHUNK(kc + 1);      // dwise chunk kc+1 -> zbuf[(kc+1)&1]  (VALU + y2 loads)
    COMPUTE(kc);          // MFMA chunk kc from As[kc&1], zbuf[kc&1]
    WRITEA(kc + 1);       // regs -> As[(kc+1)&1] (implicit vmcnt wait)
    __syncthreads();
  }
  COMPUTE(8);

#undef COMPUTE
#undef SCATs
#undef DWCHUNK
#undef LOADA
#undef WRITEA

  // ---- epilogue: BN + residual ---------------------------------------------
  if (px < 56) {
    size_t pbase = (size_t)b * COUT * NP + (size_t)h * 56 + px;
#define EPI(ACC, a) do {                                                      \
    _Pragma("unroll") for (int i = 0; i < 4; ++i) {                           \
      int o = wr * 48 + (a) * 16 + q * 4 + i;                                 \
      size_t idx = pbase + (size_t)o * NP;                                    \
      out[idx] = ACC[i] * sc3[o] + bi3[o] + x[idx];                           \
    } } while (0)
    EPI(acc0, 0); EPI(acc1, 1); EPI(acc2, 2);
#undef EPI
  }
}

// ---------------- workspace layout (bytes) -----------------------------------
#define OFF_XT     ((size_t)0)           // 19267584 (dead after expand)
#define OFF_KWT    OFF_XT                // 737280, aliases xt
#define OFF_Y      ((size_t)19267584)    // 115605504  y2 [b][p][h] bf16
#define OFF_Z      ((size_t)134873088)   // (dead; kept for xpart/yspart aliasing)
#define OFF_XPART  OFF_Z                 // 602112
#define OFF_YSPART (OFF_Z + 602112)      // 3612672
#define OFF_W1C    ((size_t)250478592)   // 3538944
#define OFF_W3C    ((size_t)254017536)   // 3538944
#define OFF_R1     ((size_t)257642496)   // 1024
#define OFF_RBLK   ((size_t)257643520)   // 1024
#define OFF_SC1    ((size_t)257645568)   // 2304
#define OFF_BI1    ((size_t)257647872)   // 2304
#define OFF_SC2    ((size_t)257650176)   // 2304
#define OFF_BI2    ((size_t)257652480)   // 2304
#define OFF_SC3    ((size_t)257654784)   // 384
#define OFF_BI3    ((size_t)257655168)   // 384

extern "C" void kernel_launch(void* const* d_in, const int* in_sizes, int n_in,
                              void* d_out, int out_size, void* d_ws, size_t ws_size,
                              hipStream_t stream) {
  const float* x   = (const float*)d_in[0];
  const float* wr1 = (const float*)d_in[1];
  const float* br1 = (const float*)d_in[2];
  const float* w1  = (const float*)d_in[3];
  const float* g1  = (const float*)d_in[4];
  const float* bt1 = (const float*)d_in[5];
  const float* m1  = (const float*)d_in[6];
  const float* v1  = (const float*)d_in[7];
  const float* wr2 = (const float*)d_in[8];
  const float* br2 = (const float*)d_in[9];
  const float* w2  = (const float*)d_in[10];
  const float* g2  = (const float*)d_in[11];
  const float* bt2 = (const float*)d_in[12];
  const float* m2  = (const float*)d_in[13];
  const float* v2  = (const float*)d_in[14];
  const float* w3  = (const float*)d_in[15];
  const float* g3  = (const float*)d_in[16];
  const float* bt3 = (const float*)d_in[17];
  const float* m3  = (const float*)d_in[18];
  const float* v3  = (const float*)d_in[19];
  const float* wr3 = (const float*)d_in[20];
  const float* br3 = (const float*)d_in[21];
  float* out = (float*)d_out;
  char* ws = (char*)d_ws;

  unsigned short* xt     = (unsigned short*)(ws + OFF_XT);
  unsigned short* y2     = (unsigned short*)(ws + OFF_Y);
  unsigned short* w1c    = (unsigned short*)(ws + OFF_W1C);
  unsigned short* w3c    = (unsigned short*)(ws + OFF_W3C);
  float* xpart  = (float*)(ws + OFF_XPART);
  float* yspart = (float*)(ws + OFF_YSPART);
  float* r1     = (float*)(ws + OFF_R1);
  float* rblk   = (float*)(ws + OFF_RBLK);
  float* sc1    = (float*)(ws + OFF_SC1);
  float* bi1    = (float*)(ws + OFF_BI1);
  float* sc2    = (float*)(ws + OFF_SC2);
  float* bi2    = (float*)(ws + OFF_BI2);
  float* sc3    = (float*)(ws + OFF_SC3);
  float* bi3    = (float*)(ws + OFF_BI3);
  float* kwt    = (float*)(ws + OFF_KWT);

  k_transpose<<<32 * 49, 256, 0, stream>>>(x, xt, xpart);
  k_front<<<532, 64, 0, stream>>>(xpart, wr1, br1, wr3, br3, r1, rblk,
                                  g1, bt1, m1, v1, g2, bt2, m2, v2, g3, bt3, m3, v3,
                                  sc1, bi1, sc2, bi2, sc3, bi3);
  k_mixw<<<432, 256, 0, stream>>>(w1, r1, w1c, w3, rblk, w3c);
  k_expand2<<<dim3(49, 9, 32), 256, 0, stream>>>(xt, w1c, sc1, bi1, y2, yspart);
  k_mid<<<32, 256, 0, stream>>>(yspart, wr2, br2, w2, sc2, bi2, kwt);
  k_dwproj2<<<dim3(56, 1, 32), 512, 0, stream>>>(y2, kwt, w3c, sc3, bi3, x, out);
}

// Round 12
// 303.838 us; speedup vs baseline: 1.8330x; 1.3916x over previous
//
#include <hip/hip_runtime.h>
#include <hip/hip_bf16.h>

#define B_   32
#define CIN  96
#define COUT 96
#define NP   3136
#define NE   8
#define HIDD 576

typedef short bf16x8 __attribute__((ext_vector_type(8)));
typedef float f32x4 __attribute__((ext_vector_type(4)));

__device__ __forceinline__ unsigned short f2bf(float f) {
  __hip_bfloat16 h = __float2bfloat16(f);
  unsigned short u; __builtin_memcpy(&u, &h, 2); return u;
}
__device__ __forceinline__ float bf2f(unsigned short u) {
  unsigned int v = ((unsigned int)u) << 16;
  float f; __builtin_memcpy(&f, &v, 4); return f;
}
__device__ __forceinline__ float u2f(unsigned int v) {
  float f; __builtin_memcpy(&f, &v, 4); return f;
}

// ---------------- kernel 1: transpose x -> x_t[b][p][c] bf16, + partial sums -
__global__ __launch_bounds__(256) void k_transpose(const float* __restrict__ x,
                                                   unsigned short* __restrict__ xt,
                                                   float* __restrict__ xpart) {
  __shared__ float tile[CIN][65];
  int bi = blockIdx.x; int b = bi / 49, pt = bi % 49; int p0 = pt * 64;
  int t = threadIdx.x;
  for (int j = t; j < CIN * 64; j += 256) {
    int c = j >> 6, pi = j & 63;
    tile[c][pi] = x[((size_t)(b * CIN + c)) * NP + p0 + pi];
  }
  __syncthreads();
  if (t < CIN) {
    float s = 0.f;
    for (int i = 0; i < 64; ++i) s += tile[t][i];
    xpart[((size_t)(b * 49 + pt)) * CIN + t] = s;
  }
  for (int j = t; j < 64 * CIN; j += 256) {
    int p = j / CIN, c = j % CIN;
    xt[((size_t)(b * NP + p0 + p)) * CIN + c] = f2bf(tile[c][p]);
  }
}

// ---------------- kernel 2: fused routers r1/rblk + BN scale/bias prep -------
__global__ __launch_bounds__(64) void k_front(const float* __restrict__ xpart,
    const float* __restrict__ wr1, const float* __restrict__ br1,
    const float* __restrict__ wr3, const float* __restrict__ br3,
    float* __restrict__ r1, float* __restrict__ rblk,
    const float* g1, const float* bt1, const float* m1, const float* v1,
    const float* g2, const float* bt2, const float* m2, const float* v2,
    const float* g3, const float* bt3, const float* m3, const float* v3,
    float* sc1, float* bi1, float* sc2, float* bi2, float* sc3, float* bi3) {
  int bi = blockIdx.x; int lane = threadIdx.x;
  if (bi < 512) {
    const float* wr; const float* br; float* dst; int id;
    if (bi < 256) { wr = wr1; br = br1; dst = r1;   id = bi; }
    else          { wr = wr3; br = br3; dst = rblk; id = bi - 256; }
    int b = id >> 3, e = id & 7;
    float s = 0.f;
    for (int c = lane; c < CIN; c += 64) {
      const float* xp = xpart + (size_t)b * 49 * CIN + c;
      float xm = 0.f;
#pragma unroll 7
      for (int k = 0; k < 49; ++k) xm += xp[k * CIN];
      s += xm * (1.0f / NP) * wr[e * CIN + c];
    }
    s += __shfl_xor(s, 1);  s += __shfl_xor(s, 2);  s += __shfl_xor(s, 4);
    s += __shfl_xor(s, 8);  s += __shfl_xor(s, 16); s += __shfl_xor(s, 32);
    if (lane == 0) dst[id] = 1.0f / (1.0f + __expf(-(s + br[e])));
  } else {
    int i = (bi - 512) * 64 + lane;
    if (i < HIDD) {
      float s = g1[i] * rsqrtf(v1[i] + 1e-5f); sc1[i] = s; bi1[i] = bt1[i] - m1[i] * s;
    } else if (i < 2 * HIDD) {
      int c = i - HIDD;
      float s = g2[c] * rsqrtf(v2[c] + 1e-5f); sc2[c] = s; bi2[c] = bt2[c] - m2[c] * s;
    } else if (i < 2 * HIDD + COUT) {
      int c = i - 2 * HIDD;
      float s = g3[c] * rsqrtf(v3[c] + 1e-5f); sc3[c] = s; bi3[c] = bt3[c] - m3[c] * s;
    }
  }
}

// ---------------- kernel 3: mix expert weights -> bf16 -----------------------
__global__ __launch_bounds__(256) void k_mixw(
    const float* __restrict__ w1, const float* __restrict__ r1, unsigned short* __restrict__ w1c,
    const float* __restrict__ w3, const float* __restrict__ rblk, unsigned short* __restrict__ w3c) {
  __shared__ float rsh[256];
  int bi = blockIdx.x; int t = threadIdx.x;
  const float* w; const float* r; unsigned short* dst; int oc0;
  if (bi < 216) { w = w1; r = r1;   dst = w1c; oc0 = bi * 256; }
  else          { w = w3; r = rblk; dst = w3c; oc0 = (bi - 216) * 256; }
  rsh[t] = r[t];
  __syncthreads();
  int oc = oc0 + t;
  float wv[NE];
#pragma unroll
  for (int e = 0; e < NE; ++e) wv[e] = w[(size_t)e * 55296 + oc];
  for (int b = 0; b < B_; ++b) {
    float a = 0.f;
#pragma unroll
    for (int e = 0; e < NE; ++e) a += rsh[b * 8 + e] * wv[e];
    dst[(size_t)b * 55296 + oc] = f2bf(a);
  }
}

// ---------------- kernel 4: expand GEMM + BN + ReLU6, y in [b][p][h] ---------
__global__ __launch_bounds__(256) void k_expand2(const unsigned short* __restrict__ xt,
    const unsigned short* __restrict__ w1c, const float* __restrict__ sc1,
    const float* __restrict__ bi1, unsigned short* __restrict__ y2,
    float* __restrict__ yspart) {
  __shared__ unsigned short As[64 * 104];   // w1c tile; reused as transpose buf T[64][72]
  __shared__ unsigned short Bs[64 * 104];   // xt tile
  int t = threadIdx.x;
  int pt = blockIdx.x;
  int p0 = pt * 64, o0 = blockIdx.y * 64, b = blockIdx.z;
  const unsigned short* ag = w1c + (size_t)b * 55296 + (size_t)o0 * 96;
  const unsigned short* bg = xt + ((size_t)b * NP + p0) * 96;
  for (int j = t; j < 768; j += 256) {
    int r = j / 12, ch = j % 12;
    *(int4*)(As + r * 104 + ch * 8) = *(const int4*)(ag + r * 96 + ch * 8);
    *(int4*)(Bs + r * 104 + ch * 8) = *(const int4*)(bg + r * 96 + ch * 8);
  }
  __syncthreads();
  int lane = t & 63, wv = t >> 6;
  int m = lane & 15, q = lane >> 4;
  f32x4 acc[4];
#pragma unroll
  for (int nt = 0; nt < 4; ++nt) acc[nt] = 0.f;
#pragma unroll
  for (int kk = 0; kk < 3; ++kk) {
    bf16x8 af = *(const bf16x8*)(As + (wv * 16 + m) * 104 + kk * 32 + q * 8);
#pragma unroll
    for (int nt = 0; nt < 4; ++nt) {
      bf16x8 bfb = *(const bf16x8*)(Bs + (nt * 16 + m) * 104 + kk * 32 + q * 8);
      acc[nt] = __builtin_amdgcn_mfma_f32_16x16x32_bf16(af, bfb, acc[nt], 0, 0, 0);
    }
  }
  __syncthreads();   // all LDS reads done; As is now free for reuse
  float sc[4], bb[4];
#pragma unroll
  for (int i = 0; i < 4; ++i) {
    int o = o0 + wv * 16 + q * 4 + i;
    sc[i] = sc1[o]; bb[i] = bi1[o];
  }
  float rs[4] = {0.f, 0.f, 0.f, 0.f};
  unsigned short* T = As;   // T stride 72 u16
#pragma unroll
  for (int nt = 0; nt < 4; ++nt) {
    unsigned short pk[4];
#pragma unroll
    for (int i = 0; i < 4; ++i) {
      float v = acc[nt][i] * sc[i] + bb[i];
      v = fminf(fmaxf(v, 0.f), 6.f);
      rs[i] += v;
      pk[i] = f2bf(v);
    }
    uint2 pv; __builtin_memcpy(&pv, pk, 8);
    *(uint2*)(T + (nt * 16 + m) * 72 + wv * 16 + q * 4) = pv;
  }
#pragma unroll
  for (int i = 0; i < 4; ++i) {
    float r = rs[i];
    r += __shfl_xor(r, 1); r += __shfl_xor(r, 2);
    r += __shfl_xor(r, 4); r += __shfl_xor(r, 8);
    if (m == 0)
      yspart[((size_t)b * 49 + pt) * HIDD + o0 + wv * 16 + q * 4 + i] = r;
  }
  __syncthreads();
  for (int j = t; j < 512; j += 256) {
    int r = j >> 3, ch = j & 7;
    *(int4*)(y2 + ((size_t)(b * NP + p0 + r)) * 576 + o0 + ch * 8) =
        *(const int4*)(T + r * 72 + ch * 8);
  }
}

// ---------------- kernel 5: fused router2 + tap premix (one block per batch) -
__global__ __launch_bounds__(256) void k_mid(const float* __restrict__ yspart,
    const float* __restrict__ wr2, const float* __restrict__ br2,
    const float* __restrict__ w2, const float* __restrict__ sc2,
    const float* __restrict__ bi2, float* __restrict__ kwt) {
  __shared__ float ysum_l[HIDD];
  __shared__ float r2_l[NE];
  int b = blockIdx.x, t = threadIdx.x;
  const float* yp = yspart + (size_t)b * 49 * HIDD;
  for (int c = t; c < HIDD; c += 256) {
    float s = 0.f;
#pragma unroll 7
    for (int k = 0; k < 49; ++k) s += yp[k * HIDD + c];
    ysum_l[c] = s;
  }
  __syncthreads();
  int wv = t >> 6, lane = t & 63;
  for (int e = wv; e < NE; e += 4) {
    float s = 0.f;
    for (int h = lane; h < HIDD; h += 64)
      s += ysum_l[h] * (1.0f / NP) * wr2[e * HIDD + h];
    s += __shfl_xor(s, 1);  s += __shfl_xor(s, 2);  s += __shfl_xor(s, 4);
    s += __shfl_xor(s, 8);  s += __shfl_xor(s, 16); s += __shfl_xor(s, 32);
    if (lane == 0) r2_l[e] = 1.0f / (1.0f + __expf(-(s + br2[e])));
  }
  __syncthreads();
  float rr[NE];
#pragma unroll
  for (int e = 0; e < NE; ++e) rr[e] = r2_l[e];
  for (int c = t; c < HIDD; c += 256) {
    float sc = sc2[c];
    float* dst = kwt + (size_t)b * 5760 + c;
#pragma unroll
    for (int k = 0; k < 9; ++k) {
      float s = 0.f;
#pragma unroll
      for (int e = 0; e < NE; ++e) s += rr[e] * w2[((size_t)e * HIDD + c) * 9 + k];
      dst[k * 576] = s * sc;
    }
    dst[9 * 576] = bi2[c];
  }
}

// ---------------- helpers for dwise math -------------------------------------
__device__ __forceinline__ f32x4 cvt4(uint2 v) {
  f32x4 r;
  r[0] = u2f(v.x << 16); r[1] = u2f(v.x & 0xffff0000u);
  r[2] = u2f(v.y << 16); r[3] = u2f(v.y & 0xffff0000u);
  return r;
}
__device__ __forceinline__ uint2 pack4(f32x4 v) {
  uint2 r;
  r.x = (unsigned)f2bf(v[0]) | ((unsigned)f2bf(v[1]) << 16);
  r.y = (unsigned)f2bf(v[2]) | ((unsigned)f2bf(v[3]) << 16);
  return r;
}
__device__ __forceinline__ f32x4 clamp6(f32x4 v) {
#pragma unroll
  for (int i = 0; i < 4; ++i) v[i] = fminf(fmaxf(v[i], 0.f), 6.f);
  return v;
}

// ---------------- kernel 6: FUSED depthwise + project GEMM + BN + residual ---
// Round-7 structure (87 us, proven) with ONE change: 576 threads (9 waves) so
// phase-1 runs exactly ONE dwise task per thread (round 7: 512 threads, 576
// tasks -> 64 threads ran 2 full tasks while 448 idled at the barrier; phase-1
// critical path was 2x). Phase-2 (LDS As ping-pong, 8 GEMM waves) unchanged;
// wave 8 only participates in barriers. __launch_bounds__(576,2) = 256-VGPR
// cap (round-10 lesson: tighter bounds force scratch spill). LDS 79.2 KB ->
// 2 blocks/CU, 18 waves. XCD row-remap kept (FETCH 229->114 MB proven).
__global__ __launch_bounds__(576, 2) void k_dwproj3(const unsigned short* __restrict__ y2,
    const float* __restrict__ kwt, const unsigned short* __restrict__ w3c,
    const float* __restrict__ sc3, const float* __restrict__ bi3,
    const float* __restrict__ x, float* __restrict__ out) {
  __shared__ unsigned short zl[56 * 584];   // 65408 B, stride 584
  __shared__ unsigned short As[96 * 72];    // 13824 B, w3c K-chunk tile
  int t = threadIdx.x;
  int hr = blockIdx.x, b = blockIdx.z;
  int h = (hr & 7) * 7 + (hr >> 3);         // XCD-contiguous row band
  const unsigned short* ag = w3c + (size_t)b * 55296;

  // ---- A staging lane map: rows 0..63 by t<512, rows 64..95 by t<256 -------
  int r0 = t >> 3, c8 = t & 7;
  int r1 = 64 + (t >> 3);
  bool one = (t < 512), two = (t < 256);
  int4 ra0, ra1;
#define LOADA(kc) do {                                                       \
    if (one) ra0 = *(const int4*)(ag + (size_t)r0 * 576 + (kc) * 64 + c8 * 8); \
    if (two) ra1 = *(const int4*)(ag + (size_t)r1 * 576 + (kc) * 64 + c8 * 8); \
  } while (0)
#define WRITEA() do {                                                        \
    if (one) *(int4*)(As + r0 * 72 + c8 * 8) = ra0;                          \
    if (two) *(int4*)(As + r1 * 72 + c8 * 8) = ra1;                          \
  } while (0)

  LOADA(0);   // issue chunk-0 A loads; latency hides under phase-1 dwise

  // ---- phase 1: depthwise 3x3 for row h, all 576 ch, into zl ---------------
  // 576 tasks on 576 threads: exactly one (4-ch group, 14-px seg) per thread.
  {
    bool okU = (h > 0), okD = (h < 55);
    int rU = okU ? (h - 1) : h;
    int rD = okD ? (h + 1) : h;
    f32x4 d0, d1, d2;
    int task = t;
    int cgi = task % 144;          // 4-channel group
    int seg = task / 144;          // 14-pixel segment
    int c = cgi * 4, w0 = seg * 14;
    const float* kp = kwt + (size_t)b * 5760 + c;
    f32x4 tk[9], tb;
#pragma unroll
    for (int k = 0; k < 9; ++k) tk[k] = *(const f32x4*)(kp + k * 576);
    tb = *(const f32x4*)(kp + 9 * 576);
    const unsigned short* yrU = y2 + ((size_t)(b * NP + rU * 56)) * 576 + c;
    const unsigned short* yrC = y2 + ((size_t)(b * NP + h  * 56)) * 576 + c;
    const unsigned short* yrD = y2 + ((size_t)(b * NP + rD * 56)) * 576 + c;

#define LOADC3(j) do {                                                       \
    uint2 q0, q1, q2;                                                        \
    q0.x = q0.y = q1.x = q1.y = q2.x = q2.y = 0u;                            \
    if ((unsigned)(j) < 56u) {                                               \
      if (okU) q0 = *(const uint2*)(yrU + (size_t)(j) * 576);                \
      q1 = *(const uint2*)(yrC + (size_t)(j) * 576);                         \
      if (okD) q2 = *(const uint2*)(yrD + (size_t)(j) * 576);                \
    }                                                                        \
    d0 = cvt4(q0); d1 = cvt4(q1); d2 = cvt4(q2);                             \
  } while (0)

#define SCAT3(A, Bv, Cv, j, STORE) do {                                      \
    LOADC3(j);                                                               \
    A  += d0 * tk[2] + d1 * tk[5] + d2 * tk[8];                              \
    Bv += d0 * tk[1] + d1 * tk[4] + d2 * tk[7];                              \
    Cv += d0 * tk[0] + d1 * tk[3] + d2 * tk[6];                              \
    if (STORE)                                                               \
      *(uint2*)(zl + (size_t)((j) - 1) * 584 + c) = pack4(clamp6(A));        \
    A = tb;                                                                  \
  } while (0)

    f32x4 Av = tb, Bv = tb, Cv = tb;
    SCAT3(Av, Bv, Cv, w0 - 1, false);
    SCAT3(Bv, Cv, Av, w0,     false);
#pragma unroll 1
    for (int u = 0; u < 4; ++u) {
      int j = w0 + 1 + u * 3;
      SCAT3(Cv, Av, Bv, j,     true);
      SCAT3(Av, Bv, Cv, j + 1, true);
      SCAT3(Bv, Cv, Av, j + 2, true);
    }
    SCAT3(Cv, Av, Bv, w0 + 13, true);      // stores output col w0+12
    LOADC3(w0 + 14);                       // final col: only kx=2 taps live
    Av += d0 * tk[2] + d1 * tk[5] + d2 * tk[8];
    *(uint2*)(zl + (size_t)(w0 + 13) * 584 + c) = pack4(clamp6(Av));
#undef SCAT3
#undef LOADC3
  }

  WRITEA();
  __syncthreads();   // zl complete + As chunk 0 ready

  // ---- phase 2: GEMM out[96 o][56 px] = w3c[96][576] x z[px][576] ----------
  int lane = t & 63, wv = t >> 6;
  int wr = (wv >> 2) & 1, wc = wv & 3;   // waves 0..7: 48 o x 16 px each
  int m = lane & 15, q = lane >> 4;
  int px = wc * 16 + m;
  int pxr = (px < 56) ? px : 55;         // clamped B-read (lanes px>=56 discarded)
  bool gemmw = (wv < 8);
  f32x4 acc0, acc1, acc2;
  acc0 = 0.f; acc1 = 0.f; acc2 = 0.f;

#define COMPUTE(kc) do {                                                     \
    _Pragma("unroll") for (int kk = 0; kk < 2; ++kk) {                       \
      bf16x8 bfv = *(const bf16x8*)(zl + (size_t)pxr * 584 + (kc) * 64 + kk * 32 + q * 8); \
      bf16x8 af0 = *(const bf16x8*)(As + (wr * 48 +  0 + m) * 72 + kk * 32 + q * 8); \
      bf16x8 af1 = *(const bf16x8*)(As + (wr * 48 + 16 + m) * 72 + kk * 32 + q * 8); \
      bf16x8 af2 = *(const bf16x8*)(As + (wr * 48 + 32 + m) * 72 + kk * 32 + q * 8); \
      acc0 = __builtin_amdgcn_mfma_f32_16x16x32_bf16(af0, bfv, acc0, 0, 0, 0); \
      acc1 = __builtin_amdgcn_mfma_f32_16x16x32_bf16(af1, bfv, acc1, 0, 0, 0); \
      acc2 = __builtin_amdgcn_mfma_f32_16x16x32_bf16(af2, bfv, acc2, 0, 0, 0); \
    } } while (0)

#pragma unroll 1
  for (int kc = 0; kc < 8; ++kc) {
    LOADA(kc + 1);             // next A chunk; latency hides under MFMA
    if (gemmw) COMPUTE(kc);    // consume current As chunk
    __syncthreads();           // As reads done
    WRITEA();                  // vmcnt wait happens here, after compute phase
    __syncthreads();           // As chunk kc+1 ready
  }
  if (gemmw) COMPUTE(8);

#undef COMPUTE
#undef LOADA
#undef WRITEA

  // ---- epilogue: BN + residual ---------------------------------------------
  if (gemmw && px < 56) {
    size_t pbase = (size_t)b * COUT * NP + (size_t)h * 56 + px;
#define EPI(ACC, a) do {                                                     \
    _Pragma("unroll") for (int i = 0; i < 4; ++i) {                          \
      int o = wr * 48 + (a) * 16 + q * 4 + i;                                \
      size_t idx = pbase + (size_t)o * NP;                                   \
      out[idx] = ACC[i] * sc3[o] + bi3[o] + x[idx];                          \
    } } while (0)
    EPI(acc0, 0); EPI(acc1, 1); EPI(acc2, 2);
#undef EPI
  }
}

// ---------------- workspace layout (bytes) -----------------------------------
#define OFF_XT     ((size_t)0)           // 19267584 (dead after expand)
#define OFF_KWT    OFF_XT                // 737280, aliases xt
#define OFF_Y      ((size_t)19267584)    // 115605504  y2 [b][p][h] bf16
#define OFF_Z      ((size_t)134873088)   // (dead; kept for xpart/yspart aliasing)
#define OFF_XPART  OFF_Z                 // 602112
#define OFF_YSPART (OFF_Z + 602112)      // 3612672
#define OFF_W1C    ((size_t)250478592)   // 3538944
#define OFF_W3C    ((size_t)254017536)   // 3538944
#define OFF_R1     ((size_t)257642496)   // 1024
#define OFF_RBLK   ((size_t)257643520)   // 1024
#define OFF_SC1    ((size_t)257645568)   // 2304
#define OFF_BI1    ((size_t)257647872)   // 2304
#define OFF_SC2    ((size_t)257650176)   // 2304
#define OFF_BI2    ((size_t)257652480)   // 2304
#define OFF_SC3    ((size_t)257654784)   // 384
#define OFF_BI3    ((size_t)257655168)   // 384

extern "C" void kernel_launch(void* const* d_in, const int* in_sizes, int n_in,
                              void* d_out, int out_size, void* d_ws, size_t ws_size,
                              hipStream_t stream) {
  const float* x   = (const float*)d_in[0];
  const float* wr1 = (const float*)d_in[1];
  const float* br1 = (const float*)d_in[2];
  const float* w1  = (const float*)d_in[3];
  const float* g1  = (const float*)d_in[4];
  const float* bt1 = (const float*)d_in[5];
  const float* m1  = (const float*)d_in[6];
  const float* v1  = (const float*)d_in[7];
  const float* wr2 = (const float*)d_in[8];
  const float* br2 = (const float*)d_in[9];
  const float* w2  = (const float*)d_in[10];
  const float* g2  = (const float*)d_in[11];
  const float* bt2 = (const float*)d_in[12];
  const float* m2  = (const float*)d_in[13];
  const float* v2  = (const float*)d_in[14];
  const float* w3  = (const float*)d_in[15];
  const float* g3  = (const float*)d_in[16];
  const float* bt3 = (const float*)d_in[17];
  const float* m3  = (const float*)d_in[18];
  const float* v3  = (const float*)d_in[19];
  const float* wr3 = (const float*)d_in[20];
  const float* br3 = (const float*)d_in[21];
  float* out = (float*)d_out;
  char* ws = (char*)d_ws;

  unsigned short* xt     = (unsigned short*)(ws + OFF_XT);
  unsigned short* y2     = (unsigned short*)(ws + OFF_Y);
  unsigned short* w1c    = (unsigned short*)(ws + OFF_W1C);
  unsigned short* w3c    = (unsigned short*)(ws + OFF_W3C);
  float* xpart  = (float*)(ws + OFF_XPART);
  float* yspart = (float*)(ws + OFF_YSPART);
  float* r1     = (float*)(ws + OFF_R1);
  float* rblk   = (float*)(ws + OFF_RBLK);
  float* sc1    = (float*)(ws + OFF_SC1);
  float* bi1    = (float*)(ws + OFF_BI1);
  float* sc2    = (float*)(ws + OFF_SC2);
  float* bi2    = (float*)(ws + OFF_BI2);
  float* sc3    = (float*)(ws + OFF_SC3);
  float* bi3    = (float*)(ws + OFF_BI3);
  float* kwt    = (float*)(ws + OFF_KWT);

  k_transpose<<<32 * 49, 256, 0, stream>>>(x, xt, xpart);
  k_front<<<532, 64, 0, stream>>>(xpart, wr1, br1, wr3, br3, r1, rblk,
                                  g1, bt1, m1, v1, g2, bt2, m2, v2, g3, bt3, m3, v3,
                                  sc1, bi1, sc2, bi2, sc3, bi3);
  k_mixw<<<432, 256, 0, stream>>>(w1, r1, w1c, w3, rblk, w3c);
  k_expand2<<<dim3(49, 9, 32), 256, 0, stream>>>(xt, w1c, sc1, bi1, y2, yspart);
  k_mid<<<32, 256, 0, stream>>>(yspart, wr2, br2, w2, sc2, bi2, kwt);
  k_dwproj3<<<dim3(56, 1, 32), 576, 0, stream>>>(y2, kwt, w3c, sc3, bi3, x, out);
}

// Round 13
// 275.901 us; speedup vs baseline: 2.0186x; 1.1013x over previous
//
#include <hip/hip_runtime.h>
#include <hip/hip_bf16.h>

#define B_   32
#define CIN  96
#define COUT 96
#define NP   3136
#define NE   8
#define HIDD 576

typedef short bf16x8 __attribute__((ext_vector_type(8)));
typedef float f32x4 __attribute__((ext_vector_type(4)));

__device__ __forceinline__ unsigned short f2bf(float f) {
  __hip_bfloat16 h = __float2bfloat16(f);
  unsigned short u; __builtin_memcpy(&u, &h, 2); return u;
}
__device__ __forceinline__ float bf2f(unsigned short u) {
  unsigned int v = ((unsigned int)u) << 16;
  float f; __builtin_memcpy(&f, &v, 4); return f;
}
__device__ __forceinline__ float u2f(unsigned int v) {
  float f; __builtin_memcpy(&f, &v, 4); return f;
}

// ---------------- kernel 1: transpose x -> x_t[b][p][c] bf16, + partial sums -
__global__ __launch_bounds__(256) void k_transpose(const float* __restrict__ x,
                                                   unsigned short* __restrict__ xt,
                                                   float* __restrict__ xpart) {
  __shared__ float tile[CIN][65];
  int bi = blockIdx.x; int b = bi / 49, pt = bi % 49; int p0 = pt * 64;
  int t = threadIdx.x;
  for (int j = t; j < CIN * 64; j += 256) {
    int c = j >> 6, pi = j & 63;
    tile[c][pi] = x[((size_t)(b * CIN + c)) * NP + p0 + pi];
  }
  __syncthreads();
  if (t < CIN) {
    float s = 0.f;
    for (int i = 0; i < 64; ++i) s += tile[t][i];
    xpart[((size_t)(b * 49 + pt)) * CIN + t] = s;
  }
  for (int j = t; j < 64 * CIN; j += 256) {
    int p = j / CIN, c = j % CIN;
    xt[((size_t)(b * NP + p0 + p)) * CIN + c] = f2bf(tile[c][p]);
  }
}

// ---------------- kernel 2: fused routers r1/rblk + BN scale/bias prep -------
__global__ __launch_bounds__(64) void k_front(const float* __restrict__ xpart,
    const float* __restrict__ wr1, const float* __restrict__ br1,
    const float* __restrict__ wr3, const float* __restrict__ br3,
    float* __restrict__ r1, float* __restrict__ rblk,
    const float* g1, const float* bt1, const float* m1, const float* v1,
    const float* g2, const float* bt2, const float* m2, const float* v2,
    const float* g3, const float* bt3, const float* m3, const float* v3,
    float* sc1, float* bi1, float* sc2, float* bi2, float* sc3, float* bi3) {
  int bi = blockIdx.x; int lane = threadIdx.x;
  if (bi < 512) {
    const float* wr; const float* br; float* dst; int id;
    if (bi < 256) { wr = wr1; br = br1; dst = r1;   id = bi; }
    else          { wr = wr3; br = br3; dst = rblk; id = bi - 256; }
    int b = id >> 3, e = id & 7;
    float s = 0.f;
    for (int c = lane; c < CIN; c += 64) {
      const float* xp = xpart + (size_t)b * 49 * CIN + c;
      float xm = 0.f;
#pragma unroll 7
      for (int k = 0; k < 49; ++k) xm += xp[k * CIN];
      s += xm * (1.0f / NP) * wr[e * CIN + c];
    }
    s += __shfl_xor(s, 1);  s += __shfl_xor(s, 2);  s += __shfl_xor(s, 4);
    s += __shfl_xor(s, 8);  s += __shfl_xor(s, 16); s += __shfl_xor(s, 32);
    if (lane == 0) dst[id] = 1.0f / (1.0f + __expf(-(s + br[e])));
  } else {
    int i = (bi - 512) * 64 + lane;
    if (i < HIDD) {
      float s = g1[i] * rsqrtf(v1[i] + 1e-5f); sc1[i] = s; bi1[i] = bt1[i] - m1[i] * s;
    } else if (i < 2 * HIDD) {
      int c = i - HIDD;
      float s = g2[c] * rsqrtf(v2[c] + 1e-5f); sc2[c] = s; bi2[c] = bt2[c] - m2[c] * s;
    } else if (i < 2 * HIDD + COUT) {
      int c = i - 2 * HIDD;
      float s = g3[c] * rsqrtf(v3[c] + 1e-5f); sc3[c] = s; bi3[c] = bt3[c] - m3[c] * s;
    }
  }
}

// ---------------- kernel 3: mix expert weights -> bf16 -----------------------
__global__ __launch_bounds__(256) void k_mixw(
    const float* __restrict__ w1, const float* __restrict__ r1, unsigned short* __restrict__ w1c,
    const float* __restrict__ w3, const float* __restrict__ rblk, unsigned short* __restrict__ w3c) {
  __shared__ float rsh[256];
  int bi = blockIdx.x; int t = threadIdx.x;
  const float* w; const float* r; unsigned short* dst; int oc0;
  if (bi < 216) { w = w1; r = r1;   dst = w1c; oc0 = bi * 256; }
  else          { w = w3; r = rblk; dst = w3c; oc0 = (bi - 216) * 256; }
  rsh[t] = r[t];
  __syncthreads();
  int oc = oc0 + t;
  float wv[NE];
#pragma unroll
  for (int e = 0; e < NE; ++e) wv[e] = w[(size_t)e * 55296 + oc];
  for (int b = 0; b < B_; ++b) {
    float a = 0.f;
#pragma unroll
    for (int e = 0; e < NE; ++e) a += rsh[b * 8 + e] * wv[e];
    dst[(size_t)b * 55296 + oc] = f2bf(a);
  }
}

// ---------------- kernel 4: expand GEMM + BN + ReLU6, y in [b][p][h] ---------
__global__ __launch_bounds__(256) void k_expand2(const unsigned short* __restrict__ xt,
    const unsigned short* __restrict__ w1c, const float* __restrict__ sc1,
    const float* __restrict__ bi1, unsigned short* __restrict__ y2,
    float* __restrict__ yspart) {
  __shared__ unsigned short As[64 * 104];   // w1c tile; reused as transpose buf T[64][72]
  __shared__ unsigned short Bs[64 * 104];   // xt tile
  int t = threadIdx.x;
  int pt = blockIdx.x;
  int p0 = pt * 64, o0 = blockIdx.y * 64, b = blockIdx.z;
  const unsigned short* ag = w1c + (size_t)b * 55296 + (size_t)o0 * 96;
  const unsigned short* bg = xt + ((size_t)b * NP + p0) * 96;
  for (int j = t; j < 768; j += 256) {
    int r = j / 12, ch = j % 12;
    *(int4*)(As + r * 104 + ch * 8) = *(const int4*)(ag + r * 96 + ch * 8);
    *(int4*)(Bs + r * 104 + ch * 8) = *(const int4*)(bg + r * 96 + ch * 8);
  }
  __syncthreads();
  int lane = t & 63, wv = t >> 6;
  int m = lane & 15, q = lane >> 4;
  f32x4 acc[4];
#pragma unroll
  for (int nt = 0; nt < 4; ++nt) acc[nt] = 0.f;
#pragma unroll
  for (int kk = 0; kk < 3; ++kk) {
    bf16x8 af = *(const bf16x8*)(As + (wv * 16 + m) * 104 + kk * 32 + q * 8);
#pragma unroll
    for (int nt = 0; nt < 4; ++nt) {
      bf16x8 bfb = *(const bf16x8*)(Bs + (nt * 16 + m) * 104 + kk * 32 + q * 8);
      acc[nt] = __builtin_amdgcn_mfma_f32_16x16x32_bf16(af, bfb, acc[nt], 0, 0, 0);
    }
  }
  __syncthreads();   // all LDS reads done; As is now free for reuse
  float sc[4], bb[4];
#pragma unroll
  for (int i = 0; i < 4; ++i) {
    int o = o0 + wv * 16 + q * 4 + i;
    sc[i] = sc1[o]; bb[i] = bi1[o];
  }
  float rs[4] = {0.f, 0.f, 0.f, 0.f};
  unsigned short* T = As;   // T stride 72 u16
#pragma unroll
  for (int nt = 0; nt < 4; ++nt) {
    unsigned short pk[4];
#pragma unroll
    for (int i = 0; i < 4; ++i) {
      float v = acc[nt][i] * sc[i] + bb[i];
      v = fminf(fmaxf(v, 0.f), 6.f);
      rs[i] += v;
      pk[i] = f2bf(v);
    }
    uint2 pv; __builtin_memcpy(&pv, pk, 8);
    *(uint2*)(T + (nt * 16 + m) * 72 + wv * 16 + q * 4) = pv;
  }
#pragma unroll
  for (int i = 0; i < 4; ++i) {
    float r = rs[i];
    r += __shfl_xor(r, 1); r += __shfl_xor(r, 2);
    r += __shfl_xor(r, 4); r += __shfl_xor(r, 8);
    if (m == 0)
      yspart[((size_t)b * 49 + pt) * HIDD + o0 + wv * 16 + q * 4 + i] = r;
  }
  __syncthreads();
  for (int j = t; j < 512; j += 256) {
    int r = j >> 3, ch = j & 7;
    *(int4*)(y2 + ((size_t)(b * NP + p0 + r)) * 576 + o0 + ch * 8) =
        *(const int4*)(T + r * 72 + ch * 8);
  }
}

// ---------------- kernel 5: fused router2 + tap premix (one block per batch) -
__global__ __launch_bounds__(256) void k_mid(const float* __restrict__ yspart,
    const float* __restrict__ wr2, const float* __restrict__ br2,
    const float* __restrict__ w2, const float* __restrict__ sc2,
    const float* __restrict__ bi2, float* __restrict__ kwt) {
  __shared__ float ysum_l[HIDD];
  __shared__ float r2_l[NE];
  int b = blockIdx.x, t = threadIdx.x;
  const float* yp = yspart + (size_t)b * 49 * HIDD;
  for (int c = t; c < HIDD; c += 256) {
    float s = 0.f;
#pragma unroll 7
    for (int k = 0; k < 49; ++k) s += yp[k * HIDD + c];
    ysum_l[c] = s;
  }
  __syncthreads();
  int wv = t >> 6, lane = t & 63;
  for (int e = wv; e < NE; e += 4) {
    float s = 0.f;
    for (int h = lane; h < HIDD; h += 64)
      s += ysum_l[h] * (1.0f / NP) * wr2[e * HIDD + h];
    s += __shfl_xor(s, 1);  s += __shfl_xor(s, 2);  s += __shfl_xor(s, 4);
    s += __shfl_xor(s, 8);  s += __shfl_xor(s, 16); s += __shfl_xor(s, 32);
    if (lane == 0) r2_l[e] = 1.0f / (1.0f + __expf(-(s + br2[e])));
  }
  __syncthreads();
  float rr[NE];
#pragma unroll
  for (int e = 0; e < NE; ++e) rr[e] = r2_l[e];
  for (int c = t; c < HIDD; c += 256) {
    float sc = sc2[c];
    float* dst = kwt + (size_t)b * 5760 + c;
#pragma unroll
    for (int k = 0; k < 9; ++k) {
      float s = 0.f;
#pragma unroll
      for (int e = 0; e < NE; ++e) s += rr[e] * w2[((size_t)e * HIDD + c) * 9 + k];
      dst[k * 576] = s * sc;
    }
    dst[9 * 576] = bi2[c];
  }
}

// ---------------- helpers for dwise math -------------------------------------
__device__ __forceinline__ f32x4 cvt4(uint2 v) {
  f32x4 r;
  r[0] = u2f(v.x << 16); r[1] = u2f(v.x & 0xffff0000u);
  r[2] = u2f(v.y << 16); r[3] = u2f(v.y & 0xffff0000u);
  return r;
}
__device__ __forceinline__ uint2 pack4(f32x4 v) {
  uint2 r;
  r.x = (unsigned)f2bf(v[0]) | ((unsigned)f2bf(v[1]) << 16);
  r.y = (unsigned)f2bf(v[2]) | ((unsigned)f2bf(v[3]) << 16);
  return r;
}
__device__ __forceinline__ f32x4 clamp6(f32x4 v) {
#pragma unroll
  for (int i = 0; i < 4; ++i) v[i] = fminf(fmaxf(v[i], 0.f), 6.f);
  return v;
}

// ---------------- kernel 6: FUSED depthwise + project GEMM + BN + residual ---
// Round-7 structure (87 us proven: 512 thr, LDS zl+As 79.2 KB, 2 blocks/CU,
// XCD row-remap) with ONE change: phase-1 tasks are 8-px segments (144 cgi x
// 7 segs = 1008 tasks) instead of 14-px (576 tasks). Round 7's worst thread
// ran 2 x 16 = 32 column-loads while 448 threads ran 16 (phase-1 critical
// path 2x); now worst = 2 x 10 = 20 (-37%). Round 12 showed the alternative
// (576 thr, 9 waves) breaks occupancy (24%), so rebalance at 512 threads.
__global__ __launch_bounds__(512, 4) void k_dwproj(const unsigned short* __restrict__ y2,
    const float* __restrict__ kwt, const unsigned short* __restrict__ w3c,
    const float* __restrict__ sc3, const float* __restrict__ bi3,
    const float* __restrict__ x, float* __restrict__ out) {
  __shared__ unsigned short zl[56 * 584];   // 65408 B, stride 584
  __shared__ unsigned short As[96 * 72];    // 13824 B, w3c K-chunk tile
  int t = threadIdx.x;
  int hr = blockIdx.x, b = blockIdx.z;
  int h = (hr & 7) * 7 + (hr >> 3);         // XCD-contiguous row band
  const unsigned short* ag = w3c + (size_t)b * 55296;

  // ---- A-prefetch lane mapping (rows 0..63 by all, 64..95 by t<256) ----
  int r0 = t >> 3, c8 = t & 7;
  int r1 = 64 + (t >> 3);           // valid only when two
  bool two = (t < 256);
  int4 ra0, ra1;
#define LOADA(kc) do {                                                       \
    ra0 = *(const int4*)(ag + (size_t)r0 * 576 + (kc) * 64 + c8 * 8);        \
    if (two) ra1 = *(const int4*)(ag + (size_t)r1 * 576 + (kc) * 64 + c8 * 8); \
  } while (0)
#define WRITEA() do {                                                        \
    *(int4*)(As + r0 * 72 + c8 * 8) = ra0;                                   \
    if (two) *(int4*)(As + r1 * 72 + c8 * 8) = ra1;                          \
  } while (0)

  LOADA(0);   // issue chunk-0 A loads; latency hides under phase-1 dwise

  // ---- phase 1: depthwise 3x3 for row h, all 576 ch, into zl --------------
  // 1008 tasks = 144 (4-ch groups) x 7 (8-px segments) on 512 threads.
  {
    bool okU = (h > 0), okD = (h < 55);
    int rU = okU ? (h - 1) : h;
    int rD = okD ? (h + 1) : h;
    f32x4 d0, d1, d2;
#pragma unroll 1
    for (int task = t; task < 1008; task += 512) {
      int cgi = task % 144;          // 4-channel group
      int seg = task / 144;          // 8-pixel segment (0..6)
      int c = cgi * 4, w0 = seg * 8;
      const float* kp = kwt + (size_t)b * 5760 + c;
      f32x4 tk[9], tb;
#pragma unroll
      for (int k = 0; k < 9; ++k) tk[k] = *(const f32x4*)(kp + k * 576);
      tb = *(const f32x4*)(kp + 9 * 576);
      const unsigned short* yrU = y2 + ((size_t)(b * NP + rU * 56)) * 576 + c;
      const unsigned short* yrC = y2 + ((size_t)(b * NP + h  * 56)) * 576 + c;
      const unsigned short* yrD = y2 + ((size_t)(b * NP + rD * 56)) * 576 + c;

#define LOADC3(j) do {                                                       \
      uint2 q0, q1, q2;                                                      \
      q0.x = q0.y = q1.x = q1.y = q2.x = q2.y = 0u;                          \
      if ((unsigned)(j) < 56u) {                                             \
        if (okU) q0 = *(const uint2*)(yrU + (size_t)(j) * 576);              \
        q1 = *(const uint2*)(yrC + (size_t)(j) * 576);                       \
        if (okD) q2 = *(const uint2*)(yrD + (size_t)(j) * 576);              \
      }                                                                      \
      d0 = cvt4(q0); d1 = cvt4(q1); d2 = cvt4(q2);                           \
    } while (0)

#define SCAT3(A, Bv, Cv, j, STORE) do {                                      \
      LOADC3(j);                                                             \
      A  += d0 * tk[2] + d1 * tk[5] + d2 * tk[8];                            \
      Bv += d0 * tk[1] + d1 * tk[4] + d2 * tk[7];                            \
      Cv += d0 * tk[0] + d1 * tk[3] + d2 * tk[6];                            \
      if (STORE)                                                             \
        *(uint2*)(zl + (size_t)((j) - 1) * 584 + c) = pack4(clamp6(A));      \
      A = tb;                                                                \
    } while (0)

      f32x4 Av = tb, Bv = tb, Cv = tb;
      SCAT3(Av, Bv, Cv, w0 - 1, false);
      SCAT3(Bv, Cv, Av, w0,     false);
      SCAT3(Cv, Av, Bv, w0 + 1, true);      // stores output col w0
      SCAT3(Av, Bv, Cv, w0 + 2, true);
      SCAT3(Bv, Cv, Av, w0 + 3, true);
      SCAT3(Cv, Av, Bv, w0 + 4, true);
      SCAT3(Av, Bv, Cv, w0 + 5, true);
      SCAT3(Bv, Cv, Av, w0 + 6, true);
      SCAT3(Cv, Av, Bv, w0 + 7, true);      // stores output col w0+6
      LOADC3(w0 + 8);                       // final col: only kx=2 taps live
      Av += d0 * tk[2] + d1 * tk[5] + d2 * tk[8];
      *(uint2*)(zl + (size_t)(w0 + 7) * 584 + c) = pack4(clamp6(Av));
#undef SCAT3
#undef LOADC3
    }
  }

  WRITEA();
  __syncthreads();   // zl complete + As chunk 0 ready

  // ---- phase 2: GEMM out[96 o][56 px] = w3c[96][576] x z[px][576] ----------
  int lane = t & 63, wv = t >> 6;
  int wr = wv >> 2, wc = wv & 3;        // wave tile: 48 o x 16 px
  int m = lane & 15, q = lane >> 4;
  int px = wc * 16 + m;
  int pxr = (px < 56) ? px : 55;        // clamped B-read (lanes px>=56 discarded)
  f32x4 acc0, acc1, acc2;
  acc0 = 0.f; acc1 = 0.f; acc2 = 0.f;

#define COMPUTE(kc) do {                                                     \
    _Pragma("unroll") for (int kk = 0; kk < 2; ++kk) {                       \
      bf16x8 bfv = *(const bf16x8*)(zl + (size_t)pxr * 584 + (kc) * 64 + kk * 32 + q * 8); \
      bf16x8 af0 = *(const bf16x8*)(As + (wr * 48 +  0 + m) * 72 + kk * 32 + q * 8); \
      bf16x8 af1 = *(const bf16x8*)(As + (wr * 48 + 16 + m) * 72 + kk * 32 + q * 8); \
      bf16x8 af2 = *(const bf16x8*)(As + (wr * 48 + 32 + m) * 72 + kk * 32 + q * 8); \
      acc0 = __builtin_amdgcn_mfma_f32_16x16x32_bf16(af0, bfv, acc0, 0, 0, 0); \
      acc1 = __builtin_amdgcn_mfma_f32_16x16x32_bf16(af1, bfv, acc1, 0, 0, 0); \
      acc2 = __builtin_amdgcn_mfma_f32_16x16x32_bf16(af2, bfv, acc2, 0, 0, 0); \
    } } while (0)

#pragma unroll 1
  for (int kc = 0; kc < 8; ++kc) {
    LOADA(kc + 1);     // next A chunk; latency hides under MFMA
    COMPUTE(kc);
    __syncthreads();   // As reads done
    WRITEA();          // vmcnt wait happens here, after a full compute phase
    __syncthreads();   // As chunk kc+1 ready
  }
  COMPUTE(8);

#undef COMPUTE
#undef LOADA
#undef WRITEA

  // ---- epilogue: BN + residual ---------------------------------------------
  if (px < 56) {
    size_t pbase = (size_t)b * COUT * NP + (size_t)h * 56 + px;
#define EPI(ACC, a) do {                                                     \
    _Pragma("unroll") for (int i = 0; i < 4; ++i) {                          \
      int o = wr * 48 + (a) * 16 + q * 4 + i;                                \
      size_t idx = pbase + (size_t)o * NP;                                   \
      out[idx] = ACC[i] * sc3[o] + bi3[o] + x[idx];                          \
    } } while (0)
    EPI(acc0, 0); EPI(acc1, 1); EPI(acc2, 2);
#undef EPI
  }
}

// ---------------- workspace layout (bytes) -----------------------------------
#define OFF_XT     ((size_t)0)           // 19267584 (dead after expand)
#define OFF_KWT    OFF_XT                // 737280, aliases xt
#define OFF_Y      ((size_t)19267584)    // 115605504  y2 [b][p][h] bf16
#define OFF_Z      ((size_t)134873088)   // (dead; kept for xpart/yspart aliasing)
#define OFF_XPART  OFF_Z                 // 602112
#define OFF_YSPART (OFF_Z + 602112)      // 3612672
#define OFF_W1C    ((size_t)250478592)   // 3538944
#define OFF_W3C    ((size_t)254017536)   // 3538944
#define OFF_R1     ((size_t)257642496)   // 1024
#define OFF_RBLK   ((size_t)257643520)   // 1024
#define OFF_SC1    ((size_t)257645568)   // 2304
#define OFF_BI1    ((size_t)257647872)   // 2304
#define OFF_SC2    ((size_t)257650176)   // 2304
#define OFF_BI2    ((size_t)257652480)   // 2304
#define OFF_SC3    ((size_t)257654784)   // 384
#define OFF_BI3    ((size_t)257655168)   // 384

extern "C" void kernel_launch(void* const* d_in, const int* in_sizes, int n_in,
                              void* d_out, int out_size, void* d_ws, size_t ws_size,
                              hipStream_t stream) {
  const float* x   = (const float*)d_in[0];
  const float* wr1 = (const float*)d_in[1];
  const float* br1 = (const float*)d_in[2];
  const float* w1  = (const float*)d_in[3];
  const float* g1  = (const float*)d_in[4];
  const float* bt1 = (const float*)d_in[5];
  const float* m1  = (const float*)d_in[6];
  const float* v1  = (const float*)d_in[7];
  const float* wr2 = (const float*)d_in[8];
  const float* br2 = (const float*)d_in[9];
  const float* w2  = (const float*)d_in[10];
  const float* g2  = (const float*)d_in[11];
  const float* bt2 = (const float*)d_in[12];
  const float* m2  = (const float*)d_in[13];
  const float* v2  = (const float*)d_in[14];
  const float* w3  = (const float*)d_in[15];
  const float* g3  = (const float*)d_in[16];
  const float* bt3 = (const float*)d_in[17];
  const float* m3  = (const float*)d_in[18];
  const float* v3  = (const float*)d_in[19];
  const float* wr3 = (const float*)d_in[20];
  const float* br3 = (const float*)d_in[21];
  float* out = (float*)d_out;
  char* ws = (char*)d_ws;

  unsigned short* xt     = (unsigned short*)(ws + OFF_XT);
  unsigned short* y2     = (unsigned short*)(ws + OFF_Y);
  unsigned short* w1c    = (unsigned short*)(ws + OFF_W1C);
  unsigned short* w3c    = (unsigned short*)(ws + OFF_W3C);
  float* xpart  = (float*)(ws + OFF_XPART);
  float* yspart = (float*)(ws + OFF_YSPART);
  float* r1     = (float*)(ws + OFF_R1);
  float* rblk   = (float*)(ws + OFF_RBLK);
  float* sc1    = (float*)(ws + OFF_SC1);
  float* bi1    = (float*)(ws + OFF_BI1);
  float* sc2    = (float*)(ws + OFF_SC2);
  float* bi2    = (float*)(ws + OFF_BI2);
  float* sc3    = (float*)(ws + OFF_SC3);
  float* bi3    = (float*)(ws + OFF_BI3);
  float* kwt    = (float*)(ws + OFF_KWT);

  k_transpose<<<32 * 49, 256, 0, stream>>>(x, xt, xpart);
  k_front<<<532, 64, 0, stream>>>(xpart, wr1, br1, wr3, br3, r1, rblk,
                                  g1, bt1, m1, v1, g2, bt2, m2, v2, g3, bt3, m3, v3,
                                  sc1, bi1, sc2, bi2, sc3, bi3);
  k_mixw<<<432, 256, 0, stream>>>(w1, r1, w1c, w3, rblk, w3c);
  k_expand2<<<dim3(49, 9, 32), 256, 0, stream>>>(xt, w1c, sc1, bi1, y2, yspart);
  k_mid<<<32, 256, 0, stream>>>(yspart, wr2, br2, w2, sc2, bi2, kwt);
  k_dwproj<<<dim3(56, 1, 32), 512, 0, stream>>>(y2, kwt, w3c, sc3, bi3, x, out);
}

// Round 14
// 272.825 us; speedup vs baseline: 2.0413x; 1.0113x over previous
//
#include <hip/hip_runtime.h>
#include <hip/hip_bf16.h>

#define B_   32
#define CIN  96
#define COUT 96
#define NP   3136
#define NE   8
#define HIDD 576

typedef short bf16x8 __attribute__((ext_vector_type(8)));
typedef float f32x4 __attribute__((ext_vector_type(4)));

__device__ __forceinline__ unsigned short f2bf(float f) {
  __hip_bfloat16 h = __float2bfloat16(f);
  unsigned short u; __builtin_memcpy(&u, &h, 2); return u;
}
__device__ __forceinline__ float bf2f(unsigned short u) {
  unsigned int v = ((unsigned int)u) << 16;
  float f; __builtin_memcpy(&f, &v, 4); return f;
}
__device__ __forceinline__ float u2f(unsigned int v) {
  float f; __builtin_memcpy(&f, &v, 4); return f;
}

// ---------------- kernel 1: transpose x -> x_t[b][p][c] bf16, + partial sums -
__global__ __launch_bounds__(256) void k_transpose(const float* __restrict__ x,
                                                   unsigned short* __restrict__ xt,
                                                   float* __restrict__ xpart) {
  __shared__ float tile[CIN][65];
  int bi = blockIdx.x; int b = bi / 49, pt = bi % 49; int p0 = pt * 64;
  int t = threadIdx.x;
  for (int j = t; j < CIN * 64; j += 256) {
    int c = j >> 6, pi = j & 63;
    tile[c][pi] = x[((size_t)(b * CIN + c)) * NP + p0 + pi];
  }
  __syncthreads();
  if (t < CIN) {
    float s = 0.f;
    for (int i = 0; i < 64; ++i) s += tile[t][i];
    xpart[((size_t)(b * 49 + pt)) * CIN + t] = s;
  }
  for (int j = t; j < 64 * CIN; j += 256) {
    int p = j / CIN, c = j % CIN;
    xt[((size_t)(b * NP + p0 + p)) * CIN + c] = f2bf(tile[c][p]);
  }
}

// ---------------- kernel 2: fused routers r1/rblk + BN scale/bias prep -------
__global__ __launch_bounds__(64) void k_front(const float* __restrict__ xpart,
    const float* __restrict__ wr1, const float* __restrict__ br1,
    const float* __restrict__ wr3, const float* __restrict__ br3,
    float* __restrict__ r1, float* __restrict__ rblk,
    const float* g1, const float* bt1, const float* m1, const float* v1,
    const float* g2, const float* bt2, const float* m2, const float* v2,
    const float* g3, const float* bt3, const float* m3, const float* v3,
    float* sc1, float* bi1, float* sc2, float* bi2, float* sc3, float* bi3) {
  int bi = blockIdx.x; int lane = threadIdx.x;
  if (bi < 512) {
    const float* wr; const float* br; float* dst; int id;
    if (bi < 256) { wr = wr1; br = br1; dst = r1;   id = bi; }
    else          { wr = wr3; br = br3; dst = rblk; id = bi - 256; }
    int b = id >> 3, e = id & 7;
    float s = 0.f;
    for (int c = lane; c < CIN; c += 64) {
      const float* xp = xpart + (size_t)b * 49 * CIN + c;
      float xm = 0.f;
#pragma unroll 7
      for (int k = 0; k < 49; ++k) xm += xp[k * CIN];
      s += xm * (1.0f / NP) * wr[e * CIN + c];
    }
    s += __shfl_xor(s, 1);  s += __shfl_xor(s, 2);  s += __shfl_xor(s, 4);
    s += __shfl_xor(s, 8);  s += __shfl_xor(s, 16); s += __shfl_xor(s, 32);
    if (lane == 0) dst[id] = 1.0f / (1.0f + __expf(-(s + br[e])));
  } else {
    int i = (bi - 512) * 64 + lane;
    if (i < HIDD) {
      float s = g1[i] * rsqrtf(v1[i] + 1e-5f); sc1[i] = s; bi1[i] = bt1[i] - m1[i] * s;
    } else if (i < 2 * HIDD) {
      int c = i - HIDD;
      float s = g2[c] * rsqrtf(v2[c] + 1e-5f); sc2[c] = s; bi2[c] = bt2[c] - m2[c] * s;
    } else if (i < 2 * HIDD + COUT) {
      int c = i - 2 * HIDD;
      float s = g3[c] * rsqrtf(v3[c] + 1e-5f); sc3[c] = s; bi3[c] = bt3[c] - m3[c] * s;
    }
  }
}

// ---------------- kernel 3: mix expert weights -> bf16 -----------------------
__global__ __launch_bounds__(256) void k_mixw(
    const float* __restrict__ w1, const float* __restrict__ r1, unsigned short* __restrict__ w1c,
    const float* __restrict__ w3, const float* __restrict__ rblk, unsigned short* __restrict__ w3c) {
  __shared__ float rsh[256];
  int bi = blockIdx.x; int t = threadIdx.x;
  const float* w; const float* r; unsigned short* dst; int oc0;
  if (bi < 216) { w = w1; r = r1;   dst = w1c; oc0 = bi * 256; }
  else          { w = w3; r = rblk; dst = w3c; oc0 = (bi - 216) * 256; }
  rsh[t] = r[t];
  __syncthreads();
  int oc = oc0 + t;
  float wv[NE];
#pragma unroll
  for (int e = 0; e < NE; ++e) wv[e] = w[(size_t)e * 55296 + oc];
  for (int b = 0; b < B_; ++b) {
    float a = 0.f;
#pragma unroll
    for (int e = 0; e < NE; ++e) a += rsh[b * 8 + e] * wv[e];
    dst[(size_t)b * 55296 + oc] = f2bf(a);
  }
}

// ---------------- kernel 4: expand GEMM + BN + ReLU6, y in [b][p][h] ---------
__global__ __launch_bounds__(256) void k_expand2(const unsigned short* __restrict__ xt,
    const unsigned short* __restrict__ w1c, const float* __restrict__ sc1,
    const float* __restrict__ bi1, unsigned short* __restrict__ y2,
    float* __restrict__ yspart) {
  __shared__ unsigned short As[64 * 104];   // w1c tile; reused as transpose buf T[64][72]
  __shared__ unsigned short Bs[64 * 104];   // xt tile
  int t = threadIdx.x;
  int pt = blockIdx.x;
  int p0 = pt * 64, o0 = blockIdx.y * 64, b = blockIdx.z;
  const unsigned short* ag = w1c + (size_t)b * 55296 + (size_t)o0 * 96;
  const unsigned short* bg = xt + ((size_t)b * NP + p0) * 96;
  for (int j = t; j < 768; j += 256) {
    int r = j / 12, ch = j % 12;
    *(int4*)(As + r * 104 + ch * 8) = *(const int4*)(ag + r * 96 + ch * 8);
    *(int4*)(Bs + r * 104 + ch * 8) = *(const int4*)(bg + r * 96 + ch * 8);
  }
  __syncthreads();
  int lane = t & 63, wv = t >> 6;
  int m = lane & 15, q = lane >> 4;
  f32x4 acc[4];
#pragma unroll
  for (int nt = 0; nt < 4; ++nt) acc[nt] = 0.f;
#pragma unroll
  for (int kk = 0; kk < 3; ++kk) {
    bf16x8 af = *(const bf16x8*)(As + (wv * 16 + m) * 104 + kk * 32 + q * 8);
#pragma unroll
    for (int nt = 0; nt < 4; ++nt) {
      bf16x8 bfb = *(const bf16x8*)(Bs + (nt * 16 + m) * 104 + kk * 32 + q * 8);
      acc[nt] = __builtin_amdgcn_mfma_f32_16x16x32_bf16(af, bfb, acc[nt], 0, 0, 0);
    }
  }
  __syncthreads();   // all LDS reads done; As is now free for reuse
  float sc[4], bb[4];
#pragma unroll
  for (int i = 0; i < 4; ++i) {
    int o = o0 + wv * 16 + q * 4 + i;
    sc[i] = sc1[o]; bb[i] = bi1[o];
  }
  float rs[4] = {0.f, 0.f, 0.f, 0.f};
  unsigned short* T = As;   // T stride 72 u16
#pragma unroll
  for (int nt = 0; nt < 4; ++nt) {
    unsigned short pk[4];
#pragma unroll
    for (int i = 0; i < 4; ++i) {
      float v = acc[nt][i] * sc[i] + bb[i];
      v = fminf(fmaxf(v, 0.f), 6.f);
      rs[i] += v;
      pk[i] = f2bf(v);
    }
    uint2 pv; __builtin_memcpy(&pv, pk, 8);
    *(uint2*)(T + (nt * 16 + m) * 72 + wv * 16 + q * 4) = pv;
  }
#pragma unroll
  for (int i = 0; i < 4; ++i) {
    float r = rs[i];
    r += __shfl_xor(r, 1); r += __shfl_xor(r, 2);
    r += __shfl_xor(r, 4); r += __shfl_xor(r, 8);
    if (m == 0)
      yspart[((size_t)b * 49 + pt) * HIDD + o0 + wv * 16 + q * 4 + i] = r;
  }
  __syncthreads();
  for (int j = t; j < 512; j += 256) {
    int r = j >> 3, ch = j & 7;
    *(int4*)(y2 + ((size_t)(b * NP + p0 + r)) * 576 + o0 + ch * 8) =
        *(const int4*)(T + r * 72 + ch * 8);
  }
}

// ---------------- kernel 5: fused router2 + tap premix (one block per batch) -
__global__ __launch_bounds__(256) void k_mid(const float* __restrict__ yspart,
    const float* __restrict__ wr2, const float* __restrict__ br2,
    const float* __restrict__ w2, const float* __restrict__ sc2,
    const float* __restrict__ bi2, float* __restrict__ kwt) {
  __shared__ float ysum_l[HIDD];
  __shared__ float r2_l[NE];
  int b = blockIdx.x, t = threadIdx.x;
  const float* yp = yspart + (size_t)b * 49 * HIDD;
  for (int c = t; c < HIDD; c += 256) {
    float s = 0.f;
#pragma unroll 7
    for (int k = 0; k < 49; ++k) s += yp[k * HIDD + c];
    ysum_l[c] = s;
  }
  __syncthreads();
  int wv = t >> 6, lane = t & 63;
  for (int e = wv; e < NE; e += 4) {
    float s = 0.f;
    for (int h = lane; h < HIDD; h += 64)
      s += ysum_l[h] * (1.0f / NP) * wr2[e * HIDD + h];
    s += __shfl_xor(s, 1);  s += __shfl_xor(s, 2);  s += __shfl_xor(s, 4);
    s += __shfl_xor(s, 8);  s += __shfl_xor(s, 16); s += __shfl_xor(s, 32);
    if (lane == 0) r2_l[e] = 1.0f / (1.0f + __expf(-(s + br2[e])));
  }
  __syncthreads();
  float rr[NE];
#pragma unroll
  for (int e = 0; e < NE; ++e) rr[e] = r2_l[e];
  for (int c = t; c < HIDD; c += 256) {
    float sc = sc2[c];
    float* dst = kwt + (size_t)b * 5760 + c;
#pragma unroll
    for (int k = 0; k < 9; ++k) {
      float s = 0.f;
#pragma unroll
      for (int e = 0; e < NE; ++e) s += rr[e] * w2[((size_t)e * HIDD + c) * 9 + k];
      dst[k * 576] = s * sc;
    }
    dst[9 * 576] = bi2[c];
  }
}

// ---------------- helpers for dwise math -------------------------------------
__device__ __forceinline__ f32x4 cvt4(uint2 v) {
  f32x4 r;
  r[0] = u2f(v.x << 16); r[1] = u2f(v.x & 0xffff0000u);
  r[2] = u2f(v.y << 16); r[3] = u2f(v.y & 0xffff0000u);
  return r;
}
__device__ __forceinline__ uint2 pack4(f32x4 v) {
  uint2 r;
  r.x = (unsigned)f2bf(v[0]) | ((unsigned)f2bf(v[1]) << 16);
  r.y = (unsigned)f2bf(v[2]) | ((unsigned)f2bf(v[3]) << 16);
  return r;
}
__device__ __forceinline__ f32x4 clamp6(f32x4 v) {
#pragma unroll
  for (int i = 0; i < 4; ++i) v[i] = fminf(fmaxf(v[i], 0.f), 6.f);
  return v;
}

// ---------------- kernel 6: FUSED depthwise + project GEMM + BN + residual ---
// Round-13 structure (75.8 us proven: 512 thr, 8-px segments, LDS zl+As
// 79.2 KB, 2 blocks/CU, XCD row-remap) with ONE change: phase-1 BATCH-LOADS
// all 10 columns of a task (30 uint2, compile-time-indexed arrays -> regs)
// before computing. Round 13's VGPR_Count=52 showed zero load pipelining:
// 20 serial load->use waits (~200cyc L2 each) per thread. One burst + one
// wait instead. Math order identical. Watch: FETCH must stay ~110 MB
// (jump = spill at the 128-VGPR (512,4) cap).
__global__ __launch_bounds__(512, 4) void k_dwproj(const unsigned short* __restrict__ y2,
    const float* __restrict__ kwt, const unsigned short* __restrict__ w3c,
    const float* __restrict__ sc3, const float* __restrict__ bi3,
    const float* __restrict__ x, float* __restrict__ out) {
  __shared__ unsigned short zl[56 * 584];   // 65408 B, stride 584
  __shared__ unsigned short As[96 * 72];    // 13824 B, w3c K-chunk tile
  int t = threadIdx.x;
  int hr = blockIdx.x, b = blockIdx.z;
  int h = (hr & 7) * 7 + (hr >> 3);         // XCD-contiguous row band
  const unsigned short* ag = w3c + (size_t)b * 55296;

  // ---- A-prefetch lane mapping (rows 0..63 by all, 64..95 by t<256) ----
  int r0 = t >> 3, c8 = t & 7;
  int r1 = 64 + (t >> 3);           // valid only when two
  bool two = (t < 256);
  int4 ra0, ra1;
#define LOADA(kc) do {                                                       \
    ra0 = *(const int4*)(ag + (size_t)r0 * 576 + (kc) * 64 + c8 * 8);        \
    if (two) ra1 = *(const int4*)(ag + (size_t)r1 * 576 + (kc) * 64 + c8 * 8); \
  } while (0)
#define WRITEA() do {                                                        \
    *(int4*)(As + r0 * 72 + c8 * 8) = ra0;                                   \
    if (two) *(int4*)(As + r1 * 72 + c8 * 8) = ra1;                          \
  } while (0)

  LOADA(0);   // issue chunk-0 A loads; latency hides under phase-1 dwise

  // ---- phase 1: depthwise 3x3 for row h, all 576 ch, into zl --------------
  // 1008 tasks = 144 (4-ch groups) x 7 (8-px segments) on 512 threads.
  // Per task: batch-load 10 columns (30 uint2) -> straight-line compute.
  {
    bool okU = (h > 0), okD = (h < 55);
    int rU = okU ? (h - 1) : h;
    int rD = okD ? (h + 1) : h;
#pragma unroll 1
    for (int task = t; task < 1008; task += 512) {
      int cgi = task % 144;          // 4-channel group
      int seg = task / 144;          // 8-pixel segment (0..6)
      int c = cgi * 4, w0 = seg * 8;
      const float* kp = kwt + (size_t)b * 5760 + c;
      f32x4 tk[9], tb;
#pragma unroll
      for (int k = 0; k < 9; ++k) tk[k] = *(const f32x4*)(kp + k * 576);
      tb = *(const f32x4*)(kp + 9 * 576);
      const unsigned short* yrU = y2 + ((size_t)(b * NP + rU * 56)) * 576 + c;
      const unsigned short* yrC = y2 + ((size_t)(b * NP + h  * 56)) * 576 + c;
      const unsigned short* yrD = y2 + ((size_t)(b * NP + rD * 56)) * 576 + c;

      // batch-load all 10 columns (j = w0-1 .. w0+8), predicated
      uint2 qU[10], qC[10], qD[10];
#pragma unroll
      for (int jj = 0; jj < 10; ++jj) {
        int j = w0 - 1 + jj;
        uint2 zU, zC, zD;
        zU.x = zU.y = zC.x = zC.y = zD.x = zD.y = 0u;
        if ((unsigned)j < 56u) {
          if (okU) zU = *(const uint2*)(yrU + (size_t)j * 576);
          zC = *(const uint2*)(yrC + (size_t)j * 576);
          if (okD) zD = *(const uint2*)(yrD + (size_t)j * 576);
        }
        qU[jj] = zU; qC[jj] = zC; qD[jj] = zD;
      }

      // straight-line 10-column scatter (compile-time jj -> registers)
#define SC(A, Bv_, Cv_, jj, STORE) do {                                      \
      f32x4 d0 = cvt4(qU[jj]), d1 = cvt4(qC[jj]), d2 = cvt4(qD[jj]);         \
      A   += d0 * tk[2] + d1 * tk[5] + d2 * tk[8];                           \
      Bv_ += d0 * tk[1] + d1 * tk[4] + d2 * tk[7];                           \
      Cv_ += d0 * tk[0] + d1 * tk[3] + d2 * tk[6];                           \
      if (STORE)                                                             \
        *(uint2*)(zl + (size_t)(w0 + (jj) - 2) * 584 + c) = pack4(clamp6(A)); \
      A = tb;                                                                \
    } while (0)

      f32x4 Av = tb, Bv = tb, Cv = tb;
      SC(Av, Bv, Cv, 0, false);
      SC(Bv, Cv, Av, 1, false);
      SC(Cv, Av, Bv, 2, true);      // stores output col w0
      SC(Av, Bv, Cv, 3, true);
      SC(Bv, Cv, Av, 4, true);
      SC(Cv, Av, Bv, 5, true);
      SC(Av, Bv, Cv, 6, true);
      SC(Bv, Cv, Av, 7, true);
      SC(Cv, Av, Bv, 8, true);      // stores output col w0+6
      {                              // final col: only kx=2 taps live
        f32x4 d0 = cvt4(qU[9]), d1 = cvt4(qC[9]), d2 = cvt4(qD[9]);
        Av += d0 * tk[2] + d1 * tk[5] + d2 * tk[8];
        *(uint2*)(zl + (size_t)(w0 + 7) * 584 + c) = pack4(clamp6(Av));
      }
#undef SC
    }
  }

  WRITEA();
  __syncthreads();   // zl complete + As chunk 0 ready

  // ---- phase 2: GEMM out[96 o][56 px] = w3c[96][576] x z[px][576] ----------
  int lane = t & 63, wv = t >> 6;
  int wr = wv >> 2, wc = wv & 3;        // wave tile: 48 o x 16 px
  int m = lane & 15, q = lane >> 4;
  int px = wc * 16 + m;
  int pxr = (px < 56) ? px : 55;        // clamped B-read (lanes px>=56 discarded)
  f32x4 acc0, acc1, acc2;
  acc0 = 0.f; acc1 = 0.f; acc2 = 0.f;

#define COMPUTE(kc) do {                                                     \
    _Pragma("unroll") for (int kk = 0; kk < 2; ++kk) {                       \
      bf16x8 bfv = *(const bf16x8*)(zl + (size_t)pxr * 584 + (kc) * 64 + kk * 32 + q * 8); \
      bf16x8 af0 = *(const bf16x8*)(As + (wr * 48 +  0 + m) * 72 + kk * 32 + q * 8); \
      bf16x8 af1 = *(const bf16x8*)(As + (wr * 48 + 16 + m) * 72 + kk * 32 + q * 8); \
      bf16x8 af2 = *(const bf16x8*)(As + (wr * 48 + 32 + m) * 72 + kk * 32 + q * 8); \
      acc0 = __builtin_amdgcn_mfma_f32_16x16x32_bf16(af0, bfv, acc0, 0, 0, 0); \
      acc1 = __builtin_amdgcn_mfma_f32_16x16x32_bf16(af1, bfv, acc1, 0, 0, 0); \
      acc2 = __builtin_amdgcn_mfma_f32_16x16x32_bf16(af2, bfv, acc2, 0, 0, 0); \
    } } while (0)

#pragma unroll 1
  for (int kc = 0; kc < 8; ++kc) {
    LOADA(kc + 1);     // next A chunk; latency hides under MFMA
    COMPUTE(kc);
    __syncthreads();   // As reads done
    WRITEA();          // vmcnt wait happens here, after a full compute phase
    __syncthreads();   // As chunk kc+1 ready
  }
  COMPUTE(8);

#undef COMPUTE
#undef LOADA
#undef WRITEA

  // ---- epilogue: BN + residual ---------------------------------------------
  if (px < 56) {
    size_t pbase = (size_t)b * COUT * NP + (size_t)h * 56 + px;
#define EPI(ACC, a) do {                                                     \
    _Pragma("unroll") for (int i = 0; i < 4; ++i) {                          \
      int o = wr * 48 + (a) * 16 + q * 4 + i;                                \
      size_t idx = pbase + (size_t)o * NP;                                   \
      out[idx] = ACC[i] * sc3[o] + bi3[o] + x[idx];                          \
    } } while (0)
    EPI(acc0, 0); EPI(acc1, 1); EPI(acc2, 2);
#undef EPI
  }
}

// ---------------- workspace layout (bytes) -----------------------------------
#define OFF_XT     ((size_t)0)           // 19267584 (dead after expand)
#define OFF_KWT    OFF_XT                // 737280, aliases xt
#define OFF_Y      ((size_t)19267584)    // 115605504  y2 [b][p][h] bf16
#define OFF_Z      ((size_t)134873088)   // (dead; kept for xpart/yspart aliasing)
#define OFF_XPART  OFF_Z                 // 602112
#define OFF_YSPART (OFF_Z + 602112)      // 3612672
#define OFF_W1C    ((size_t)250478592)   // 3538944
#define OFF_W3C    ((size_t)254017536)   // 3538944
#define OFF_R1     ((size_t)257642496)   // 1024
#define OFF_RBLK   ((size_t)257643520)   // 1024
#define OFF_SC1    ((size_t)257645568)   // 2304
#define OFF_BI1    ((size_t)257647872)   // 2304
#define OFF_SC2    ((size_t)257650176)   // 2304
#define OFF_BI2    ((size_t)257652480)   // 2304
#define OFF_SC3    ((size_t)257654784)   // 384
#define OFF_BI3    ((size_t)257655168)   // 384

extern "C" void kernel_launch(void* const* d_in, const int* in_sizes, int n_in,
                              void* d_out, int out_size, void* d_ws, size_t ws_size,
                              hipStream_t stream) {
  const float* x   = (const float*)d_in[0];
  const float* wr1 = (const float*)d_in[1];
  const float* br1 = (const float*)d_in[2];
  const float* w1  = (const float*)d_in[3];
  const float* g1  = (const float*)d_in[4];
  const float* bt1 = (const float*)d_in[5];
  const float* m1  = (const float*)d_in[6];
  const float* v1  = (const float*)d_in[7];
  const float* wr2 = (const float*)d_in[8];
  const float* br2 = (const float*)d_in[9];
  const float* w2  = (const float*)d_in[10];
  const float* g2  = (const float*)d_in[11];
  const float* bt2 = (const float*)d_in[12];
  const float* m2  = (const float*)d_in[13];
  const float* v2  = (const float*)d_in[14];
  const float* w3  = (const float*)d_in[15];
  const float* g3  = (const float*)d_in[16];
  const float* bt3 = (const float*)d_in[17];
  const float* m3  = (const float*)d_in[18];
  const float* v3  = (const float*)d_in[19];
  const float* wr3 = (const float*)d_in[20];
  const float* br3 = (const float*)d_in[21];
  float* out = (float*)d_out;
  char* ws = (char*)d_ws;

  unsigned short* xt     = (unsigned short*)(ws + OFF_XT);
  unsigned short* y2     = (unsigned short*)(ws + OFF_Y);
  unsigned short* w1c    = (unsigned short*)(ws + OFF_W1C);
  unsigned short* w3c    = (unsigned short*)(ws + OFF_W3C);
  float* xpart  = (float*)(ws + OFF_XPART);
  float* yspart = (float*)(ws + OFF_YSPART);
  float* r1     = (float*)(ws + OFF_R1);
  float* rblk   = (float*)(ws + OFF_RBLK);
  float* sc1    = (float*)(ws + OFF_SC1);
  float* bi1    = (float*)(ws + OFF_BI1);
  float* sc2    = (float*)(ws + OFF_SC2);
  float* bi2    = (float*)(ws + OFF_BI2);
  float* sc3    = (float*)(ws + OFF_SC3);
  float* bi3    = (float*)(ws + OFF_BI3);
  float* kwt    = (float*)(ws + OFF_KWT);

  k_transpose<<<32 * 49, 256, 0, stream>>>(x, xt, xpart);
  k_front<<<532, 64, 0, stream>>>(xpart, wr1, br1, wr3, br3, r1, rblk,
                                  g1, bt1, m1, v1, g2, bt2, m2, v2, g3, bt3, m3, v3,
                                  sc1, bi1, sc2, bi2, sc3, bi3);
  k_mixw<<<432, 256, 0, stream>>>(w1, r1, w1c, w3, rblk, w3c);
  k_expand2<<<dim3(49, 9, 32), 256, 0, stream>>>(xt, w1c, sc1, bi1, y2, yspart);
  k_mid<<<32, 256, 0, stream>>>(yspart, wr2, br2, w2, sc2, bi2, kwt);
  k_dwproj<<<dim3(56, 1, 32), 512, 0, stream>>>(y2, kwt, w3c, sc3, bi3, x, out);
}